// Round 4
// baseline (683.816 us; speedup 1.0000x reference)
//
#include <hip/hip_runtime.h>
#include <hip/hip_bf16.h>
#include <hip/hip_fp16.h>
#include <math.h>

// GAT 3-layer net, v4.
//  - Inputs fp32 (PROVEN round 3: dtype-detector branch flip eliminated NaN).
//  - Output fp32 (harness header: output dtype follows reference = float32;
//    v3's 0.099 absmax matches "bf16 written into fp32 buffer" exactly).
//  - CSR-by-dst build, one wave per dst node, lane = feature, online softmax.
//  - Layer-1 h is recomputed per edge from x[s,0..2] + register W1 columns
//    (no h1 buffer, 16B/edge instead of 256B/edge gather).
//  - Layer-2 feats fused into layer-1 agg epilogue (shfl + LDS W2);
//    layer-3 feats fused into layer-2 agg epilogue.
//  - h2 stored fp32 if ws allows (~36 MB total), else fp16 (~23 MB).

#define NEG_BIG (-1e30f)

__device__ inline float waveSum(float v) {
#pragma unroll
  for (int off = 32; off; off >>= 1) v += __shfl_xor(v, off, 64);
  return v;
}

__device__ inline float ldh(const void* h, size_t i, int hf32) {
  return hf32 ? ((const float*)h)[i] : __half2float(((const __half*)h)[i]);
}

__device__ inline void sth(void* h, size_t i, int hf32, float v) {
  if (hf32) ((float*)h)[i] = v;
  else ((__half*)h)[i] = __float2half(v);
}

// ---------- CSR build ----------
__global__ void k_count(const int* __restrict__ dst, int* __restrict__ counts, int E) {
  int e = blockIdx.x * blockDim.x + threadIdx.x;
  if (e < E) atomicAdd(&counts[dst[e]], 1);
}

__global__ void k_blocksum(const int* __restrict__ counts, int* __restrict__ bsum, int N) {
  __shared__ int s[256];
  int i = blockIdx.x * 256 + threadIdx.x;
  s[threadIdx.x] = (i < N) ? counts[i] : 0;
  __syncthreads();
  for (int off = 128; off; off >>= 1) {
    if (threadIdx.x < off) s[threadIdx.x] += s[threadIdx.x + off];
    __syncthreads();
  }
  if (threadIdx.x == 0) bsum[blockIdx.x] = s[0];
}

__global__ void k_scanb(int* bsum, int NB) {
  __shared__ int s[1024];
  int t = threadIdx.x;
  int v = (t < NB) ? bsum[t] : 0;
  s[t] = v;
  __syncthreads();
  for (int off = 1; off < 1024; off <<= 1) {
    int u = (t >= off) ? s[t - off] : 0;
    __syncthreads();
    s[t] += u;
    __syncthreads();
  }
  if (t < NB) bsum[t] = s[t] - v;  // exclusive
}

__global__ void k_scan(const int* __restrict__ counts, const int* __restrict__ boff,
                       int* __restrict__ start, int* __restrict__ cursor, int N, int E) {
  __shared__ int s[256];
  int t = threadIdx.x;
  int i = blockIdx.x * 256 + t;
  int v = (i < N) ? counts[i] : 0;
  s[t] = v;
  __syncthreads();
  for (int off = 1; off < 256; off <<= 1) {
    int u = (t >= off) ? s[t - off] : 0;
    __syncthreads();
    s[t] += u;
    __syncthreads();
  }
  if (i < N) {
    int st = boff[blockIdx.x] + s[t] - v;
    start[i] = st;
    cursor[i] = st;
  }
  if (blockIdx.x == 0 && t == 0) start[N] = E;
}

__global__ void k_scatter(const int* __restrict__ src, const int* __restrict__ dst,
                          int* __restrict__ cursor, int* __restrict__ csr, int E) {
  int e = blockIdx.x * blockDim.x + threadIdx.x;
  if (e < E) {
    int pos = atomicAdd(&cursor[dst[e]], 1);
    csr[pos] = src[e];
  }
}

// ---------- layer 1: el1/er1 only (h1 recomputed later per edge) ----------
__global__ __launch_bounds__(256) void k_feat1(
    const float* __restrict__ x, const float* __restrict__ W,
    const float* __restrict__ al, const float* __restrict__ ar,
    float* __restrict__ el, float* __restrict__ er, int N) {
  int wave = threadIdx.x >> 6, lane = threadIdx.x & 63;
  int n = blockIdx.x * 4 + wave;
  if (n >= N) return;
  float x0 = x[n * 3 + 0], x1 = x[n * 3 + 1], x2 = x[n * 3 + 2];
  float hv = x0 * W[lane] + x1 * W[64 + lane] + x2 * W[128 + lane];
  float e1 = waveSum(hv * al[lane]);
  float e2 = waveSum(hv * ar[lane]);
  if (lane == 0) { el[n] = e1; er[n] = e2; }
}

// ---------- layer-1 aggregate (h1 on the fly) + fused layer-2 feats ----------
__global__ __launch_bounds__(256) void k_agg1f(
    const float* __restrict__ x, const float* __restrict__ W1,
    const float* __restrict__ el, const float* __restrict__ er,
    const int* __restrict__ start, const int* __restrict__ csr,
    const float* __restrict__ b1, const float* __restrict__ W2,
    const float* __restrict__ al2, const float* __restrict__ ar2,
    void* __restrict__ h2, int hf32, float* __restrict__ el2,
    float* __restrict__ er2, int N) {
  __shared__ float sW[64 * 64];
  int tid = threadIdx.x;
  for (int i = tid; i < 4096; i += 256) sW[i] = W2[i];
  __syncthreads();
  int wave = tid >> 6, lane = tid & 63;
  int n = blockIdx.x * 4 + wave;
  if (n >= N) return;
  float w1a = W1[lane], w1b = W1[64 + lane], w1c = W1[128 + lane];
  int beg = start[n], end = start[n + 1];
  float ern = er[n];
  float m = NEG_BIG, d = 0.f, o = 0.f;
  for (int p = beg; p < end; p++) {
    int s = csr[p];
    s = ((unsigned)s < (unsigned)N) ? s : 0;  // defensive
    float e = el[s] + ern;
    e = e > 0.f ? e : 0.2f * e;               // attn leaky_relu(0.2)
    float x0 = x[s * 3 + 0], x1 = x[s * 3 + 1], x2 = x[s * 3 + 2];
    float hv = x0 * w1a + x1 * w1b + x2 * w1c;  // h1[s][lane] recomputed
    if (e > m) {                              // wave-uniform
      float sc = __expf(m - e);
      d = d * sc + 1.f;
      o = o * sc + hv;
      m = e;
    } else {
      float w = __expf(e - m);
      d += w;
      o += w * hv;
    }
  }
  float r = (end > beg) ? o / d : 0.f;
  r += b1[lane];
  r = r > 0.f ? r : 0.01f * r;                // leaky_relu(0.01)
  float acc = 0.f;
#pragma unroll
  for (int k = 0; k < 64; k++) acc += __shfl(r, k, 64) * sW[k * 64 + lane];
  sth(h2, (size_t)n * 64 + lane, hf32, acc);
  float e1 = waveSum(acc * al2[lane]);
  float e2 = waveSum(acc * ar2[lane]);
  if (lane == 0) { el2[n] = e1; er2[n] = e2; }
}

// ---------- layer-2 aggregate + fused layer-3 feats ----------
__global__ __launch_bounds__(256) void k_agg2f(
    const void* __restrict__ h2, int hf32, const float* __restrict__ el,
    const float* __restrict__ er, const int* __restrict__ start,
    const int* __restrict__ csr, const float* __restrict__ b2,
    const float* __restrict__ W3, const float* __restrict__ al3,
    const float* __restrict__ ar3, float* __restrict__ h3,
    float* __restrict__ el3, float* __restrict__ er3, int N) {
  int wave = threadIdx.x >> 6, lane = threadIdx.x & 63;
  int n = blockIdx.x * 4 + wave;
  if (n >= N) return;
  int beg = start[n], end = start[n + 1];
  float ern = er[n];
  float m = NEG_BIG, d = 0.f, o = 0.f;
  for (int p = beg; p < end; p++) {
    int s = csr[p];
    s = ((unsigned)s < (unsigned)N) ? s : 0;
    float e = el[s] + ern;
    e = e > 0.f ? e : 0.2f * e;
    float hv = ldh(h2, (size_t)s * 64 + lane, hf32);
    if (e > m) {
      float sc = __expf(m - e);
      d = d * sc + 1.f;
      o = o * sc + hv;
      m = e;
    } else {
      float w = __expf(e - m);
      d += w;
      o += w * hv;
    }
  }
  float r = (end > beg) ? o / d : 0.f;
  r += b2[lane];
  r = r > 0.f ? r : 0.01f * r;
  float p0 = waveSum(r * W3[lane * 3 + 0]);
  float p1 = waveSum(r * W3[lane * 3 + 1]);
  float p2 = waveSum(r * W3[lane * 3 + 2]);
  if (lane == 0) {
    h3[n * 3 + 0] = p0; h3[n * 3 + 1] = p1; h3[n * 3 + 2] = p2;
    el3[n] = p0 * al3[0] + p1 * al3[1] + p2 * al3[2];
    er3[n] = p0 * ar3[0] + p1 * ar3[1] + p2 * ar3[2];
  }
}

// ---------- final aggregate (Fout=3) -> fp32 output ----------
__global__ void k_agg3(const float* __restrict__ h3, const float* __restrict__ el,
                       const float* __restrict__ er, const int* __restrict__ start,
                       const int* __restrict__ csr, const float* __restrict__ b,
                       float* __restrict__ out, int N) {
  int n = blockIdx.x * blockDim.x + threadIdx.x;
  if (n >= N) return;
  int beg = start[n], end = start[n + 1];
  float ern = er[n];
  float m = NEG_BIG, d = 0.f, o0 = 0.f, o1 = 0.f, o2 = 0.f;
  for (int p = beg; p < end; p++) {
    int s = csr[p];
    s = ((unsigned)s < (unsigned)N) ? s : 0;
    float e = el[s] + ern;
    e = e > 0.f ? e : 0.2f * e;
    float w;
    if (e > m) {
      float sc = __expf(m - e);
      d *= sc; o0 *= sc; o1 *= sc; o2 *= sc;
      m = e;
      w = 1.f;
    } else {
      w = __expf(e - m);
    }
    d += w;
    o0 += w * h3[s * 3 + 0];
    o1 += w * h3[s * 3 + 1];
    o2 += w * h3[s * 3 + 2];
  }
  float inv = (end > beg) ? 1.f / d : 0.f;
  out[n * 3 + 0] = o0 * inv + b[0];
  out[n * 3 + 1] = o1 * inv + b[1];
  out[n * 3 + 2] = o2 * inv + b[2];
}

extern "C" void kernel_launch(void* const* d_in, const int* in_sizes, int n_in,
                              void* d_out, int out_size, void* d_ws, size_t ws_size,
                              hipStream_t stream) {
  const int N = in_sizes[0] / 3;
  const int E = in_sizes[1];
  const float* feats = (const float*)d_in[0];
  const int* src = (const int*)d_in[1];
  const int* dst = (const int*)d_in[2];
  const float* W1  = (const float*)d_in[3];
  const float* al1 = (const float*)d_in[4];
  const float* ar1 = (const float*)d_in[5];
  const float* b1  = (const float*)d_in[6];
  const float* W2  = (const float*)d_in[7];
  const float* al2 = (const float*)d_in[8];
  const float* ar2 = (const float*)d_in[9];
  const float* b2  = (const float*)d_in[10];
  const float* W3  = (const float*)d_in[11];
  const float* al3 = (const float*)d_in[12];
  const float* ar3 = (const float*)d_in[13];
  const float* b3  = (const float*)d_in[14];

  char* ws = (char*)d_ws;
  size_t off = 0;
  auto alloc = [&](size_t bytes) -> void* {
    void* p = ws + off;
    off = (off + bytes + 255) & ~(size_t)255;
    return p;
  };
  // small/critical arrays first (~10.6 MB), h2 last with dtype fallback
  int* counts = (int*)alloc((size_t)N * 4);
  int* startv = (int*)alloc((size_t)(N + 1) * 4);
  int* cursor = (int*)alloc((size_t)N * 4);
  int* csr    = (int*)alloc((size_t)E * 4);
  float* elA  = (float*)alloc((size_t)N * 4);   // layer1 el, then layer3 el
  float* erA  = (float*)alloc((size_t)N * 4);   // layer1 er, then layer3 er
  float* elB  = (float*)alloc((size_t)N * 4);   // layer2 el
  float* erB  = (float*)alloc((size_t)N * 4);   // layer2 er
  int* bsum   = (int*)alloc(1024 * 4);
  float* h3   = (float*)alloc((size_t)N * 3 * 4);
  const int hf32 = (off + (size_t)N * 64 * 4 <= ws_size) ? 1 : 0;
  void* h2 = alloc((size_t)N * 64 * (hf32 ? 4 : 2));

  const int NB  = (N + 255) / 256;
  const int NB4 = (N + 3) / 4;
  const int EB  = (E + 255) / 256;

  hipMemsetAsync(counts, 0, (size_t)N * 4, stream);
  k_count<<<EB, 256, 0, stream>>>(dst, counts, E);
  k_blocksum<<<NB, 256, 0, stream>>>(counts, bsum, N);
  k_scanb<<<1, 1024, 0, stream>>>(bsum, NB);
  k_scan<<<NB, 256, 0, stream>>>(counts, bsum, startv, cursor, N, E);
  k_scatter<<<EB, 256, 0, stream>>>(src, dst, cursor, csr, E);

  k_feat1<<<NB4, 256, 0, stream>>>(feats, W1, al1, ar1, elA, erA, N);
  k_agg1f<<<NB4, 256, 0, stream>>>(feats, W1, elA, erA, startv, csr, b1,
                                   W2, al2, ar2, h2, hf32, elB, erB, N);
  k_agg2f<<<NB4, 256, 0, stream>>>(h2, hf32, elB, erB, startv, csr, b2,
                                   W3, al3, ar3, h3, elA, erA, N);
  k_agg3<<<(N + 255) / 256, 256, 0, stream>>>(h3, elA, erA, startv, csr, b3,
                                              (float*)d_out, N);
}

// Round 5
// 560.258 us; speedup vs baseline: 1.2205x; 1.2205x over previous
//
#include <hip/hip_runtime.h>
#include <hip/hip_fp16.h>
#include <math.h>

// GAT 3-layer net, v5 (first perf round; v4 passed at 684 us).
//  - fp32 in/out (proven). h2 stored fp16 always (ws<36MB forced it in v4;
//    absmax 4.9e-4 vs 1.8e-3 threshold -> fine, and halves gather bytes).
//  - Edge loops restructured: 4 edges per iteration, blocked online-softmax
//    (one rescale per batch), readfirstlane -> csr/el/x reads become scalar
//    s_loads (kill per-lane replicated addr-calc + VMEM; 4 gathers in
//    flight instead of ~1). v4 counters: k_agg1f hbm 2.5%, VALU 49%,
//    occupancy 80% => latency-bound serial chain, this attacks exactly that.

#define NEG_BIG (-1e30f)

__device__ inline float waveSum(float v) {
#pragma unroll
  for (int off = 32; off; off >>= 1) v += __shfl_xor(v, off, 64);
  return v;
}

// ---------- CSR build ----------
__global__ void k_count(const int* __restrict__ dst, int* __restrict__ counts, int E) {
  int e = blockIdx.x * blockDim.x + threadIdx.x;
  if (e < E) atomicAdd(&counts[dst[e]], 1);
}

__global__ void k_blocksum(const int* __restrict__ counts, int* __restrict__ bsum, int N) {
  __shared__ int s[256];
  int i = blockIdx.x * 256 + threadIdx.x;
  s[threadIdx.x] = (i < N) ? counts[i] : 0;
  __syncthreads();
  for (int off = 128; off; off >>= 1) {
    if (threadIdx.x < off) s[threadIdx.x] += s[threadIdx.x + off];
    __syncthreads();
  }
  if (threadIdx.x == 0) bsum[blockIdx.x] = s[0];
}

__global__ void k_scanb(int* bsum, int NB) {
  __shared__ int s[1024];
  int t = threadIdx.x;
  int v = (t < NB) ? bsum[t] : 0;
  s[t] = v;
  __syncthreads();
  for (int off = 1; off < 1024; off <<= 1) {
    int u = (t >= off) ? s[t - off] : 0;
    __syncthreads();
    s[t] += u;
    __syncthreads();
  }
  if (t < NB) bsum[t] = s[t] - v;  // exclusive
}

__global__ void k_scan(const int* __restrict__ counts, const int* __restrict__ boff,
                       int* __restrict__ start, int* __restrict__ cursor, int N, int E) {
  __shared__ int s[256];
  int t = threadIdx.x;
  int i = blockIdx.x * 256 + t;
  int v = (i < N) ? counts[i] : 0;
  s[t] = v;
  __syncthreads();
  for (int off = 1; off < 256; off <<= 1) {
    int u = (t >= off) ? s[t - off] : 0;
    __syncthreads();
    s[t] += u;
    __syncthreads();
  }
  if (i < N) {
    int st = boff[blockIdx.x] + s[t] - v;
    start[i] = st;
    cursor[i] = st;
  }
  if (blockIdx.x == 0 && t == 0) start[N] = E;
}

__global__ void k_scatter(const int* __restrict__ src, const int* __restrict__ dst,
                          int* __restrict__ cursor, int* __restrict__ csr, int E) {
  int e = blockIdx.x * blockDim.x + threadIdx.x;
  if (e < E) {
    int pos = atomicAdd(&cursor[dst[e]], 1);
    csr[pos] = src[e];
  }
}

// ---------- layer 1: el1/er1 only (h1 recomputed per edge later) ----------
__global__ __launch_bounds__(256) void k_feat1(
    const float* __restrict__ x, const float* __restrict__ W,
    const float* __restrict__ al, const float* __restrict__ ar,
    float* __restrict__ el, float* __restrict__ er, int N) {
  int wave = threadIdx.x >> 6, lane = threadIdx.x & 63;
  int n = blockIdx.x * 4 + wave;
  if (n >= N) return;
  float x0 = x[n * 3 + 0], x1 = x[n * 3 + 1], x2 = x[n * 3 + 2];
  float hv = x0 * W[lane] + x1 * W[64 + lane] + x2 * W[128 + lane];
  float e1 = waveSum(hv * al[lane]);
  float e2 = waveSum(hv * ar[lane]);
  if (lane == 0) { el[n] = e1; er[n] = e2; }
}

// ---------- layer-1 aggregate (h1 on the fly) + fused layer-2 feats ----------
__global__ __launch_bounds__(256) void k_agg1f(
    const float* __restrict__ x, const float* __restrict__ W1,
    const float* __restrict__ el, const float* __restrict__ er,
    const int* __restrict__ start, const int* __restrict__ csr,
    const float* __restrict__ b1, const float* __restrict__ W2,
    const float* __restrict__ al2, const float* __restrict__ ar2,
    __half* __restrict__ h2, float* __restrict__ el2,
    float* __restrict__ er2, int N) {
  __shared__ float sW[64 * 64];
  int tid = threadIdx.x;
  for (int i = tid; i < 4096; i += 256) sW[i] = W2[i];
  __syncthreads();
  int wave = tid >> 6, lane = tid & 63;
  int n = blockIdx.x * 4 + wave;
  if (n >= N) return;
  float w1a = W1[lane], w1b = W1[64 + lane], w1c = W1[128 + lane];
  int beg = __builtin_amdgcn_readfirstlane(start[n]);
  int end = __builtin_amdgcn_readfirstlane(start[n + 1]);
  float ern = er[n];
  float m = NEG_BIG, d = 0.f, o = 0.f;
  for (int p = beg; p < end; p += 4) {
    int v1 = (p + 1 < end), v2 = (p + 2 < end), v3 = (p + 3 < end);
    int p1 = v1 ? p + 1 : p, p2 = v2 ? p + 2 : p, p3 = v3 ? p + 3 : p;
    int s0 = __builtin_amdgcn_readfirstlane(csr[p]);
    int s1 = __builtin_amdgcn_readfirstlane(csr[p1]);
    int s2 = __builtin_amdgcn_readfirstlane(csr[p2]);
    int s3 = __builtin_amdgcn_readfirstlane(csr[p3]);
    s0 = ((unsigned)s0 < (unsigned)N) ? s0 : 0;
    s1 = ((unsigned)s1 < (unsigned)N) ? s1 : 0;
    s2 = ((unsigned)s2 < (unsigned)N) ? s2 : 0;
    s3 = ((unsigned)s3 < (unsigned)N) ? s3 : 0;
    float e0 = el[s0] + ern, e1 = el[s1] + ern;
    float e2 = el[s2] + ern, e3 = el[s3] + ern;
    e0 = e0 > 0.f ? e0 : 0.2f * e0;
    e1 = e1 > 0.f ? e1 : 0.2f * e1;
    e2 = e2 > 0.f ? e2 : 0.2f * e2;
    e3 = e3 > 0.f ? e3 : 0.2f * e3;
    e1 = v1 ? e1 : NEG_BIG;
    e2 = v2 ? e2 : NEG_BIG;
    e3 = v3 ? e3 : NEG_BIG;
    // h1 rows recomputed from x (scalar loads, 12B/edge)
    float ha = x[s0 * 3] * w1a + x[s0 * 3 + 1] * w1b + x[s0 * 3 + 2] * w1c;
    float hb = x[s1 * 3] * w1a + x[s1 * 3 + 1] * w1b + x[s1 * 3 + 2] * w1c;
    float hc = x[s2 * 3] * w1a + x[s2 * 3 + 1] * w1b + x[s2 * 3 + 2] * w1c;
    float hd = x[s3 * 3] * w1a + x[s3 * 3 + 1] * w1b + x[s3 * 3 + 2] * w1c;
    float emax = fmaxf(fmaxf(e0, e1), fmaxf(e2, e3));
    float mn = fmaxf(m, emax);
    float sc = __expf(m - mn);  // first batch: exp(-1e30)=0
    float q0 = __expf(e0 - mn), q1 = __expf(e1 - mn);
    float q2 = __expf(e2 - mn), q3 = __expf(e3 - mn);
    d = d * sc + ((q0 + q1) + (q2 + q3));
    o = o * sc + ((q0 * ha + q1 * hb) + (q2 * hc + q3 * hd));
    m = mn;
  }
  float r = (end > beg) ? o / d : 0.f;
  r += b1[lane];
  r = r > 0.f ? r : 0.01f * r;  // leaky_relu(0.01)
  float acc = 0.f;
#pragma unroll
  for (int k = 0; k < 64; k++) acc += __shfl(r, k, 64) * sW[k * 64 + lane];
  h2[(size_t)n * 64 + lane] = __float2half(acc);
  float e1s = waveSum(acc * al2[lane]);
  float e2s = waveSum(acc * ar2[lane]);
  if (lane == 0) { el2[n] = e1s; er2[n] = e2s; }
}

// ---------- layer-2 aggregate + fused layer-3 feats ----------
__global__ __launch_bounds__(256) void k_agg2f(
    const __half* __restrict__ h2, const float* __restrict__ el,
    const float* __restrict__ er, const int* __restrict__ start,
    const int* __restrict__ csr, const float* __restrict__ b2,
    const float* __restrict__ W3, const float* __restrict__ al3,
    const float* __restrict__ ar3, float* __restrict__ h3,
    float* __restrict__ el3, float* __restrict__ er3, int N) {
  int wave = threadIdx.x >> 6, lane = threadIdx.x & 63;
  int n = blockIdx.x * 4 + wave;
  if (n >= N) return;
  int beg = __builtin_amdgcn_readfirstlane(start[n]);
  int end = __builtin_amdgcn_readfirstlane(start[n + 1]);
  float ern = er[n];
  float m = NEG_BIG, d = 0.f, o = 0.f;
  for (int p = beg; p < end; p += 4) {
    int v1 = (p + 1 < end), v2 = (p + 2 < end), v3 = (p + 3 < end);
    int p1 = v1 ? p + 1 : p, p2 = v2 ? p + 2 : p, p3 = v3 ? p + 3 : p;
    int s0 = __builtin_amdgcn_readfirstlane(csr[p]);
    int s1 = __builtin_amdgcn_readfirstlane(csr[p1]);
    int s2 = __builtin_amdgcn_readfirstlane(csr[p2]);
    int s3 = __builtin_amdgcn_readfirstlane(csr[p3]);
    s0 = ((unsigned)s0 < (unsigned)N) ? s0 : 0;
    s1 = ((unsigned)s1 < (unsigned)N) ? s1 : 0;
    s2 = ((unsigned)s2 < (unsigned)N) ? s2 : 0;
    s3 = ((unsigned)s3 < (unsigned)N) ? s3 : 0;
    float e0 = el[s0] + ern, e1 = el[s1] + ern;
    float e2 = el[s2] + ern, e3 = el[s3] + ern;
    e0 = e0 > 0.f ? e0 : 0.2f * e0;
    e1 = e1 > 0.f ? e1 : 0.2f * e1;
    e2 = e2 > 0.f ? e2 : 0.2f * e2;
    e3 = e3 > 0.f ? e3 : 0.2f * e3;
    e1 = v1 ? e1 : NEG_BIG;
    e2 = v2 ? e2 : NEG_BIG;
    e3 = v3 ? e3 : NEG_BIG;
    // 4 independent coalesced 128B row gathers in flight
    float ha = __half2float(h2[(size_t)s0 * 64 + lane]);
    float hb = __half2float(h2[(size_t)s1 * 64 + lane]);
    float hc = __half2float(h2[(size_t)s2 * 64 + lane]);
    float hd = __half2float(h2[(size_t)s3 * 64 + lane]);
    float emax = fmaxf(fmaxf(e0, e1), fmaxf(e2, e3));
    float mn = fmaxf(m, emax);
    float sc = __expf(m - mn);
    float q0 = __expf(e0 - mn), q1 = __expf(e1 - mn);
    float q2 = __expf(e2 - mn), q3 = __expf(e3 - mn);
    d = d * sc + ((q0 + q1) + (q2 + q3));
    o = o * sc + ((q0 * ha + q1 * hb) + (q2 * hc + q3 * hd));
    m = mn;
  }
  float r = (end > beg) ? o / d : 0.f;
  r += b2[lane];
  r = r > 0.f ? r : 0.01f * r;
  float p0 = waveSum(r * W3[lane * 3 + 0]);
  float p1 = waveSum(r * W3[lane * 3 + 1]);
  float p2 = waveSum(r * W3[lane * 3 + 2]);
  if (lane == 0) {
    h3[n * 3 + 0] = p0; h3[n * 3 + 1] = p1; h3[n * 3 + 2] = p2;
    el3[n] = p0 * al3[0] + p1 * al3[1] + p2 * al3[2];
    er3[n] = p0 * ar3[0] + p1 * ar3[1] + p2 * ar3[2];
  }
}

// ---------- final aggregate (Fout=3) -> fp32 output ----------
__global__ void k_agg3(const float* __restrict__ h3, const float* __restrict__ el,
                       const float* __restrict__ er, const int* __restrict__ start,
                       const int* __restrict__ csr, const float* __restrict__ b,
                       float* __restrict__ out, int N) {
  int n = blockIdx.x * blockDim.x + threadIdx.x;
  if (n >= N) return;
  int beg = start[n], end = start[n + 1];
  float ern = er[n];
  float m = NEG_BIG, d = 0.f, a0 = 0.f, a1 = 0.f, a2 = 0.f;
  for (int p = beg; p < end; p += 4) {
    int v1 = (p + 1 < end), v2 = (p + 2 < end), v3 = (p + 3 < end);
    int p1 = v1 ? p + 1 : p, p2 = v2 ? p + 2 : p, p3 = v3 ? p + 3 : p;
    int s0 = csr[p], s1 = csr[p1], s2 = csr[p2], s3 = csr[p3];
    s0 = ((unsigned)s0 < (unsigned)N) ? s0 : 0;
    s1 = ((unsigned)s1 < (unsigned)N) ? s1 : 0;
    s2 = ((unsigned)s2 < (unsigned)N) ? s2 : 0;
    s3 = ((unsigned)s3 < (unsigned)N) ? s3 : 0;
    float e0 = el[s0] + ern, e1 = el[s1] + ern;
    float e2 = el[s2] + ern, e3 = el[s3] + ern;
    e0 = e0 > 0.f ? e0 : 0.2f * e0;
    e1 = e1 > 0.f ? e1 : 0.2f * e1;
    e2 = e2 > 0.f ? e2 : 0.2f * e2;
    e3 = e3 > 0.f ? e3 : 0.2f * e3;
    e1 = v1 ? e1 : NEG_BIG;
    e2 = v2 ? e2 : NEG_BIG;
    e3 = v3 ? e3 : NEG_BIG;
    float b00 = h3[s0 * 3], b01 = h3[s0 * 3 + 1], b02 = h3[s0 * 3 + 2];
    float b10 = h3[s1 * 3], b11 = h3[s1 * 3 + 1], b12 = h3[s1 * 3 + 2];
    float b20 = h3[s2 * 3], b21 = h3[s2 * 3 + 1], b22 = h3[s2 * 3 + 2];
    float b30 = h3[s3 * 3], b31 = h3[s3 * 3 + 1], b32 = h3[s3 * 3 + 2];
    float emax = fmaxf(fmaxf(e0, e1), fmaxf(e2, e3));
    float mn = fmaxf(m, emax);
    float sc = __expf(m - mn);
    float q0 = __expf(e0 - mn), q1 = __expf(e1 - mn);
    float q2 = __expf(e2 - mn), q3 = __expf(e3 - mn);
    d = d * sc + ((q0 + q1) + (q2 + q3));
    a0 = a0 * sc + ((q0 * b00 + q1 * b10) + (q2 * b20 + q3 * b30));
    a1 = a1 * sc + ((q0 * b01 + q1 * b11) + (q2 * b21 + q3 * b31));
    a2 = a2 * sc + ((q0 * b02 + q1 * b12) + (q2 * b22 + q3 * b32));
    m = mn;
  }
  float inv = (end > beg) ? 1.f / d : 0.f;
  out[n * 3 + 0] = a0 * inv + b[0];
  out[n * 3 + 1] = a1 * inv + b[1];
  out[n * 3 + 2] = a2 * inv + b[2];
}

extern "C" void kernel_launch(void* const* d_in, const int* in_sizes, int n_in,
                              void* d_out, int out_size, void* d_ws, size_t ws_size,
                              hipStream_t stream) {
  const int N = in_sizes[0] / 3;
  const int E = in_sizes[1];
  const float* feats = (const float*)d_in[0];
  const int* src = (const int*)d_in[1];
  const int* dst = (const int*)d_in[2];
  const float* W1  = (const float*)d_in[3];
  const float* al1 = (const float*)d_in[4];
  const float* ar1 = (const float*)d_in[5];
  const float* b1  = (const float*)d_in[6];
  const float* W2  = (const float*)d_in[7];
  const float* al2 = (const float*)d_in[8];
  const float* ar2 = (const float*)d_in[9];
  const float* b2  = (const float*)d_in[10];
  const float* W3  = (const float*)d_in[11];
  const float* al3 = (const float*)d_in[12];
  const float* ar3 = (const float*)d_in[13];
  const float* b3  = (const float*)d_in[14];

  char* ws = (char*)d_ws;
  size_t off = 0;
  auto alloc = [&](size_t bytes) -> void* {
    void* p = ws + off;
    off = (off + bytes + 255) & ~(size_t)255;
    return p;
  };
  int* counts = (int*)alloc((size_t)N * 4);
  int* startv = (int*)alloc((size_t)(N + 1) * 4);
  int* cursor = (int*)alloc((size_t)N * 4);
  int* csr    = (int*)alloc((size_t)E * 4);
  float* elA  = (float*)alloc((size_t)N * 4);
  float* erA  = (float*)alloc((size_t)N * 4);
  float* elB  = (float*)alloc((size_t)N * 4);
  float* erB  = (float*)alloc((size_t)N * 4);
  int* bsum   = (int*)alloc(1024 * 4);
  float* h3   = (float*)alloc((size_t)N * 3 * 4);
  __half* h2  = (__half*)alloc((size_t)N * 64 * 2);  // total ~23.6 MB

  const int NB  = (N + 255) / 256;
  const int NB4 = (N + 3) / 4;
  const int EB  = (E + 255) / 256;

  hipMemsetAsync(counts, 0, (size_t)N * 4, stream);
  k_count<<<EB, 256, 0, stream>>>(dst, counts, E);
  k_blocksum<<<NB, 256, 0, stream>>>(counts, bsum, N);
  k_scanb<<<1, 1024, 0, stream>>>(bsum, NB);
  k_scan<<<NB, 256, 0, stream>>>(counts, bsum, startv, cursor, N, E);
  k_scatter<<<EB, 256, 0, stream>>>(src, dst, cursor, csr, E);

  k_feat1<<<NB4, 256, 0, stream>>>(feats, W1, al1, ar1, elA, erA, N);
  k_agg1f<<<NB4, 256, 0, stream>>>(feats, W1, elA, erA, startv, csr, b1,
                                   W2, al2, ar2, h2, elB, erB, N);
  k_agg2f<<<NB4, 256, 0, stream>>>(h2, elB, erB, startv, csr, b2,
                                   W3, al3, ar3, h3, elA, erA, N);
  k_agg3<<<(N + 255) / 256, 256, 0, stream>>>(h3, elA, erA, startv, csr, b3,
                                              (float*)d_out, N);
}

// Round 6
// 531.278 us; speedup vs baseline: 1.2871x; 1.0545x over previous
//
#include <hip/hip_runtime.h>
#include <hip/hip_fp16.h>
#include <math.h>

// GAT 3-layer net, v6.
//  - v5 post-mortem: 4-edge batching kept a serial s_load chain (~100cyc/edge)
//    and 64x-replicated softmax VALU. v6: phase A lane=edge (coalesced csr
//    load, parallel el gather, one exp per edge, wave-reduce max/sum);
//    phase B lane=feature (a_j/s_j via v_readlane from registers, only the
//    h-row gather remains in the loop, 4 in flight).
//  - deg<=64 single-chunk fast path; generic two-pass path for any degree.
//  - Final layer edge-parallel: lane gathers float4 h3 row, 3 waveSums.
//  - fp32 in/out (proven r3/r4); h2 fp16 (absmax 4.9e-4 < 1.8e-3 thr).

#define NEG_BIG (-1e30f)

__device__ inline float waveSum(float v) {
#pragma unroll
  for (int off = 32; off; off >>= 1) v += __shfl_xor(v, off, 64);
  return v;
}

__device__ inline float waveMax(float v) {
#pragma unroll
  for (int off = 32; off; off >>= 1) v = fmaxf(v, __shfl_xor(v, off, 64));
  return v;
}

__device__ inline int rlI(int v, int l) { return __builtin_amdgcn_readlane(v, l); }
__device__ inline float rlF(float v, int l) {
  return __int_as_float(__builtin_amdgcn_readlane(__float_as_int(v), l));
}

// ---------- CSR build ----------
__global__ void k_count(const int* __restrict__ dst, int* __restrict__ counts, int E) {
  int e = blockIdx.x * blockDim.x + threadIdx.x;
  if (e < E) atomicAdd(&counts[dst[e]], 1);
}

__global__ void k_blocksum(const int* __restrict__ counts, int* __restrict__ bsum, int N) {
  __shared__ int s[256];
  int i = blockIdx.x * 256 + threadIdx.x;
  s[threadIdx.x] = (i < N) ? counts[i] : 0;
  __syncthreads();
  for (int off = 128; off; off >>= 1) {
    if (threadIdx.x < off) s[threadIdx.x] += s[threadIdx.x + off];
    __syncthreads();
  }
  if (threadIdx.x == 0) bsum[blockIdx.x] = s[0];
}

__global__ void k_scanb(int* bsum, int NB) {
  __shared__ int s[1024];
  int t = threadIdx.x;
  int v = (t < NB) ? bsum[t] : 0;
  s[t] = v;
  __syncthreads();
  for (int off = 1; off < 1024; off <<= 1) {
    int u = (t >= off) ? s[t - off] : 0;
    __syncthreads();
    s[t] += u;
    __syncthreads();
  }
  if (t < NB) bsum[t] = s[t] - v;  // exclusive
}

__global__ void k_scan(const int* __restrict__ counts, const int* __restrict__ boff,
                       int* __restrict__ start, int* __restrict__ cursor, int N, int E) {
  __shared__ int s[256];
  int t = threadIdx.x;
  int i = blockIdx.x * 256 + t;
  int v = (i < N) ? counts[i] : 0;
  s[t] = v;
  __syncthreads();
  for (int off = 1; off < 256; off <<= 1) {
    int u = (t >= off) ? s[t - off] : 0;
    __syncthreads();
    s[t] += u;
    __syncthreads();
  }
  if (i < N) {
    int st = boff[blockIdx.x] + s[t] - v;
    start[i] = st;
    cursor[i] = st;
  }
  if (blockIdx.x == 0 && t == 0) start[N] = E;
}

__global__ void k_scatter(const int* __restrict__ src, const int* __restrict__ dst,
                          int* __restrict__ cursor, int* __restrict__ csr, int E) {
  int e = blockIdx.x * blockDim.x + threadIdx.x;
  if (e < E) {
    int pos = atomicAdd(&cursor[dst[e]], 1);
    csr[pos] = src[e];
  }
}

// ---------- layer 1: el1/er1 (h1 recomputed per edge later) ----------
__global__ __launch_bounds__(256) void k_feat1(
    const float* __restrict__ x, const float* __restrict__ W,
    const float* __restrict__ al, const float* __restrict__ ar,
    float* __restrict__ el, float* __restrict__ er, int N) {
  int wave = threadIdx.x >> 6, lane = threadIdx.x & 63;
  int n = blockIdx.x * 4 + wave;
  if (n >= N) return;
  float x0 = x[n * 3 + 0], x1 = x[n * 3 + 1], x2 = x[n * 3 + 2];
  float hv = x0 * W[lane] + x1 * W[64 + lane] + x2 * W[128 + lane];
  float e1 = waveSum(hv * al[lane]);
  float e2 = waveSum(hv * ar[lane]);
  if (lane == 0) { el[n] = e1; er[n] = e2; }
}

// attention weights for this wave's node: returns per-lane a (lane=edge),
// per-lane s (edge src). Single-chunk fast path; generic fallback.
#define ATTN_PROLOG(EL)                                                       \
  int beg = __builtin_amdgcn_readfirstlane(start[n]);                         \
  int end = __builtin_amdgcn_readfirstlane(start[n + 1]);                     \
  int deg = end - beg;                                                        \
  float ern = er[n];                                                          \
  (void)ern;

// ---------- layer-1 aggregate (h1 on the fly) + fused layer-2 feats ----------
__global__ __launch_bounds__(256) void k_agg1f(
    const float* __restrict__ x, const float* __restrict__ W1,
    const float* __restrict__ el, const float* __restrict__ er,
    const int* __restrict__ start, const int* __restrict__ csr,
    const float* __restrict__ b1, const float* __restrict__ W2,
    const float* __restrict__ al2, const float* __restrict__ ar2,
    __half* __restrict__ h2, float* __restrict__ el2,
    float* __restrict__ er2, int N) {
  __shared__ float sW[64 * 64];
  int tid = threadIdx.x;
  for (int i = tid; i < 4096; i += 256) sW[i] = W2[i];
  __syncthreads();
  int wave = tid >> 6, lane = tid & 63;
  int n = blockIdx.x * 4 + wave;
  if (n >= N) return;
  ATTN_PROLOG(el)
  float w1a = W1[lane], w1b = W1[64 + lane], w1c = W1[128 + lane];
  float o = 0.f;

  if (deg > 0 && deg <= 64) {
    // phase A: lane = edge
    int idx = beg + lane;
    int s = (idx < end) ? csr[idx] : 0;
    s = ((unsigned)s < (unsigned)N) ? s : 0;
    float e = el[s] + ern;
    e = e > 0.f ? e : 0.2f * e;
    e = (idx < end) ? e : NEG_BIG;
    float m = waveMax(e);
    float q = __expf(e - m);                 // invalid lanes -> 0
    float invd = 1.f / waveSum(q);
    float a = q * invd;
    // phase B: lane = feature, serial over deg edges from registers
    int j = 0;
    for (; j + 3 < deg; j += 4) {
      int s0 = rlI(s, j), s1 = rlI(s, j + 1), s2 = rlI(s, j + 2), s3 = rlI(s, j + 3);
      float a0 = rlF(a, j), a1 = rlF(a, j + 1), a2 = rlF(a, j + 2), a3 = rlF(a, j + 3);
      float h0 = x[s0 * 3] * w1a + x[s0 * 3 + 1] * w1b + x[s0 * 3 + 2] * w1c;
      float h1 = x[s1 * 3] * w1a + x[s1 * 3 + 1] * w1b + x[s1 * 3 + 2] * w1c;
      float h2v = x[s2 * 3] * w1a + x[s2 * 3 + 1] * w1b + x[s2 * 3 + 2] * w1c;
      float h3v = x[s3 * 3] * w1a + x[s3 * 3 + 1] * w1b + x[s3 * 3 + 2] * w1c;
      o += (a0 * h0 + a1 * h1) + (a2 * h2v + a3 * h3v);
    }
    for (; j < deg; j++) {
      int s0 = rlI(s, j);
      float a0 = rlF(a, j);
      o += a0 * (x[s0 * 3] * w1a + x[s0 * 3 + 1] * w1b + x[s0 * 3 + 2] * w1c);
    }
  } else if (deg > 64) {
    // generic two-pass
    float m = NEG_BIG, d = 0.f;
    for (int base = beg; base < end; base += 64) {
      int idx = base + lane;
      int s = (idx < end) ? csr[idx] : 0;
      s = ((unsigned)s < (unsigned)N) ? s : 0;
      float e = el[s] + ern;
      e = e > 0.f ? e : 0.2f * e;
      e = (idx < end) ? e : NEG_BIG;
      float mn = fmaxf(m, waveMax(e));
      d = d * __expf(m - mn) + waveSum(__expf(e - mn));
      m = mn;
    }
    float invd = 1.f / d;
    for (int base = beg; base < end; base += 64) {
      int idx = base + lane;
      int s = (idx < end) ? csr[idx] : 0;
      s = ((unsigned)s < (unsigned)N) ? s : 0;
      float e = el[s] + ern;
      e = e > 0.f ? e : 0.2f * e;
      float a = (idx < end) ? __expf(e - m) * invd : 0.f;
      int cnt = end - base; cnt = cnt > 64 ? 64 : cnt;
      for (int j = 0; j < cnt; j++) {
        int s0 = rlI(s, j);
        float a0 = rlF(a, j);
        o += a0 * (x[s0 * 3] * w1a + x[s0 * 3 + 1] * w1b + x[s0 * 3 + 2] * w1c);
      }
    }
  }
  float r = o + b1[lane];
  r = r > 0.f ? r : 0.01f * r;               // leaky_relu(0.01)
  float acc = 0.f;
#pragma unroll
  for (int k = 0; k < 64; k++) acc += __shfl(r, k, 64) * sW[k * 64 + lane];
  h2[(size_t)n * 64 + lane] = __float2half(acc);
  float e1s = waveSum(acc * al2[lane]);
  float e2s = waveSum(acc * ar2[lane]);
  if (lane == 0) { el2[n] = e1s; er2[n] = e2s; }
}

// ---------- layer-2 aggregate + fused layer-3 feats (h3 padded to 4) -------
__global__ __launch_bounds__(256) void k_agg2f(
    const __half* __restrict__ h2, const float* __restrict__ el,
    const float* __restrict__ er, const int* __restrict__ start,
    const int* __restrict__ csr, const float* __restrict__ b2,
    const float* __restrict__ W3, const float* __restrict__ al3,
    const float* __restrict__ ar3, float* __restrict__ h3,
    float* __restrict__ el3, float* __restrict__ er3, int N) {
  int wave = threadIdx.x >> 6, lane = threadIdx.x & 63;
  int n = blockIdx.x * 4 + wave;
  if (n >= N) return;
  ATTN_PROLOG(el)
  float o = 0.f;

  if (deg > 0 && deg <= 64) {
    int idx = beg + lane;
    int s = (idx < end) ? csr[idx] : 0;
    s = ((unsigned)s < (unsigned)N) ? s : 0;
    float e = el[s] + ern;
    e = e > 0.f ? e : 0.2f * e;
    e = (idx < end) ? e : NEG_BIG;
    float m = waveMax(e);
    float q = __expf(e - m);
    float invd = 1.f / waveSum(q);
    float a = q * invd;
    int j = 0;
    for (; j + 3 < deg; j += 4) {
      int s0 = rlI(s, j), s1 = rlI(s, j + 1), s2 = rlI(s, j + 2), s3 = rlI(s, j + 3);
      float a0 = rlF(a, j), a1 = rlF(a, j + 1), a2 = rlF(a, j + 2), a3 = rlF(a, j + 3);
      float ha = __half2float(h2[(size_t)s0 * 64 + lane]);
      float hb = __half2float(h2[(size_t)s1 * 64 + lane]);
      float hc = __half2float(h2[(size_t)s2 * 64 + lane]);
      float hd = __half2float(h2[(size_t)s3 * 64 + lane]);
      o += (a0 * ha + a1 * hb) + (a2 * hc + a3 * hd);
    }
    for (; j < deg; j++) {
      int s0 = rlI(s, j);
      float a0 = rlF(a, j);
      o += a0 * __half2float(h2[(size_t)s0 * 64 + lane]);
    }
  } else if (deg > 64) {
    float m = NEG_BIG, d = 0.f;
    for (int base = beg; base < end; base += 64) {
      int idx = base + lane;
      int s = (idx < end) ? csr[idx] : 0;
      s = ((unsigned)s < (unsigned)N) ? s : 0;
      float e = el[s] + ern;
      e = e > 0.f ? e : 0.2f * e;
      e = (idx < end) ? e : NEG_BIG;
      float mn = fmaxf(m, waveMax(e));
      d = d * __expf(m - mn) + waveSum(__expf(e - mn));
      m = mn;
    }
    float invd = 1.f / d;
    for (int base = beg; base < end; base += 64) {
      int idx = base + lane;
      int s = (idx < end) ? csr[idx] : 0;
      s = ((unsigned)s < (unsigned)N) ? s : 0;
      float e = el[s] + ern;
      e = e > 0.f ? e : 0.2f * e;
      float a = (idx < end) ? __expf(e - m) * invd : 0.f;
      int cnt = end - base; cnt = cnt > 64 ? 64 : cnt;
      for (int j = 0; j < cnt; j++) {
        int s0 = rlI(s, j);
        float a0 = rlF(a, j);
        o += a0 * __half2float(h2[(size_t)s0 * 64 + lane]);
      }
    }
  }
  float r = o + b2[lane];
  r = r > 0.f ? r : 0.01f * r;
  float p0 = waveSum(r * W3[lane * 3 + 0]);
  float p1 = waveSum(r * W3[lane * 3 + 1]);
  float p2 = waveSum(r * W3[lane * 3 + 2]);
  if (lane == 0) {
    h3[n * 4 + 0] = p0; h3[n * 4 + 1] = p1; h3[n * 4 + 2] = p2; h3[n * 4 + 3] = 0.f;
    el3[n] = p0 * al3[0] + p1 * al3[1] + p2 * al3[2];
    er3[n] = p0 * ar3[0] + p1 * ar3[1] + p2 * ar3[2];
  }
}

// ---------- final aggregate (Fout=3), fully edge-parallel ----------
__global__ __launch_bounds__(256) void k_agg3(
    const float4* __restrict__ h3, const float* __restrict__ el,
    const float* __restrict__ er, const int* __restrict__ start,
    const int* __restrict__ csr, const float* __restrict__ b,
    float* __restrict__ out, int N) {
  int wave = threadIdx.x >> 6, lane = threadIdx.x & 63;
  int n = blockIdx.x * 4 + wave;
  if (n >= N) return;
  ATTN_PROLOG(el)
  float o0 = 0.f, o1 = 0.f, o2 = 0.f;

  if (deg > 0 && deg <= 64) {
    int idx = beg + lane;
    int s = (idx < end) ? csr[idx] : 0;
    s = ((unsigned)s < (unsigned)N) ? s : 0;
    float e = el[s] + ern;
    e = e > 0.f ? e : 0.2f * e;
    e = (idx < end) ? e : NEG_BIG;
    float m = waveMax(e);
    float q = __expf(e - m);
    float invd = 1.f / waveSum(q);
    float a = q * invd;
    float4 hv = h3[s];                       // 16B gather per lane
    o0 = waveSum(a * hv.x);
    o1 = waveSum(a * hv.y);
    o2 = waveSum(a * hv.z);
  } else if (deg > 64) {
    float m = NEG_BIG, d = 0.f;
    for (int base = beg; base < end; base += 64) {
      int idx = base + lane;
      int s = (idx < end) ? csr[idx] : 0;
      s = ((unsigned)s < (unsigned)N) ? s : 0;
      float e = el[s] + ern;
      e = e > 0.f ? e : 0.2f * e;
      e = (idx < end) ? e : NEG_BIG;
      float mn = fmaxf(m, waveMax(e));
      d = d * __expf(m - mn) + waveSum(__expf(e - mn));
      m = mn;
    }
    float invd = 1.f / d;
    for (int base = beg; base < end; base += 64) {
      int idx = base + lane;
      int s = (idx < end) ? csr[idx] : 0;
      s = ((unsigned)s < (unsigned)N) ? s : 0;
      float e = el[s] + ern;
      e = e > 0.f ? e : 0.2f * e;
      float a = (idx < end) ? __expf(e - m) * invd : 0.f;
      float4 hv = h3[s];
      o0 += waveSum(a * hv.x);
      o1 += waveSum(a * hv.y);
      o2 += waveSum(a * hv.z);
    }
  }
  if (lane == 0) {
    out[n * 3 + 0] = o0 + b[0];
    out[n * 3 + 1] = o1 + b[1];
    out[n * 3 + 2] = o2 + b[2];
  }
}

extern "C" void kernel_launch(void* const* d_in, const int* in_sizes, int n_in,
                              void* d_out, int out_size, void* d_ws, size_t ws_size,
                              hipStream_t stream) {
  const int N = in_sizes[0] / 3;
  const int E = in_sizes[1];
  const float* feats = (const float*)d_in[0];
  const int* src = (const int*)d_in[1];
  const int* dst = (const int*)d_in[2];
  const float* W1  = (const float*)d_in[3];
  const float* al1 = (const float*)d_in[4];
  const float* ar1 = (const float*)d_in[5];
  const float* b1  = (const float*)d_in[6];
  const float* W2  = (const float*)d_in[7];
  const float* al2 = (const float*)d_in[8];
  const float* ar2 = (const float*)d_in[9];
  const float* b2  = (const float*)d_in[10];
  const float* W3  = (const float*)d_in[11];
  const float* al3 = (const float*)d_in[12];
  const float* ar3 = (const float*)d_in[13];
  const float* b3  = (const float*)d_in[14];

  char* ws = (char*)d_ws;
  size_t off = 0;
  auto alloc = [&](size_t bytes) -> void* {
    void* p = ws + off;
    off = (off + bytes + 255) & ~(size_t)255;
    return p;
  };
  int* counts = (int*)alloc((size_t)N * 4);
  int* startv = (int*)alloc((size_t)(N + 1) * 4);
  int* cursor = (int*)alloc((size_t)N * 4);
  int* csr    = (int*)alloc((size_t)E * 4);
  float* elA  = (float*)alloc((size_t)N * 4);
  float* erA  = (float*)alloc((size_t)N * 4);
  float* elB  = (float*)alloc((size_t)N * 4);
  float* erB  = (float*)alloc((size_t)N * 4);
  int* bsum   = (int*)alloc(1024 * 4);
  float* h3   = (float*)alloc((size_t)N * 4 * 4);    // padded [N,4]
  __half* h2  = (__half*)alloc((size_t)N * 64 * 2);  // total ~24 MB

  const int NB  = (N + 255) / 256;
  const int NB4 = (N + 3) / 4;
  const int EB  = (E + 255) / 256;

  hipMemsetAsync(counts, 0, (size_t)N * 4, stream);
  k_count<<<EB, 256, 0, stream>>>(dst, counts, E);
  k_blocksum<<<NB, 256, 0, stream>>>(counts, bsum, N);
  k_scanb<<<1, 1024, 0, stream>>>(bsum, NB);
  k_scan<<<NB, 256, 0, stream>>>(counts, bsum, startv, cursor, N, E);
  k_scatter<<<EB, 256, 0, stream>>>(src, dst, cursor, csr, E);

  k_feat1<<<NB4, 256, 0, stream>>>(feats, W1, al1, ar1, elA, erA, N);
  k_agg1f<<<NB4, 256, 0, stream>>>(feats, W1, elA, erA, startv, csr, b1,
                                   W2, al2, ar2, h2, elB, erB, N);
  k_agg2f<<<NB4, 256, 0, stream>>>(h2, elB, erB, startv, csr, b2,
                                   W3, al3, ar3, h3, elA, erA, N);
  k_agg3<<<NB4, 256, 0, stream>>>((const float4*)h3, elA, erA, startv, csr, b3,
                                  (float*)d_out, N);
}

// Round 7
// 515.471 us; speedup vs baseline: 1.3266x; 1.0307x over previous
//
#include <hip/hip_runtime.h>
#include <hip/hip_fp16.h>
#include <math.h>

// GAT 3-layer net, v7.
//  - Linearity: sum_j a_j*(x_j@W1) = (sum_j a_j*x_j)@W1 -> layer-1 phase B
//    (serial per-edge feature loop) deleted; aggregate 3-dim x edge-parallel.
//  - el1[s] = x[s]·(W1@al1), er1[n] = x[n]·(W1@ar1): u,v precomputed by
//    k_prep -> layer-1 attention needs NO el gather (same x[s] load serves
//    logit + aggregation). k_feat1 + el1/er1 buffers deleted.
//  - Layer-3 logits from the float4 h3 gather itself -> el3/er3 deleted.
//  - Layer-2 (nonlinear boundary) keeps gather; phase B unrolled x8.
//  - fp32 in/out (proven r3/r4); h2 fp16 (absmax 4.9e-4 << 1.8e-3 thr).

#define NEG_BIG (-1e30f)

__device__ inline float waveSum(float v) {
#pragma unroll
  for (int off = 32; off; off >>= 1) v += __shfl_xor(v, off, 64);
  return v;
}

__device__ inline float waveMax(float v) {
#pragma unroll
  for (int off = 32; off; off >>= 1) v = fmaxf(v, __shfl_xor(v, off, 64));
  return v;
}

__device__ inline int rlI(int v, int l) { return __builtin_amdgcn_readlane(v, l); }
__device__ inline float rlF(float v, int l) {
  return __int_as_float(__builtin_amdgcn_readlane(__float_as_int(v), l));
}

// ---------- CSR build ----------
__global__ void k_count(const int* __restrict__ dst, int* __restrict__ counts, int E) {
  int e = blockIdx.x * blockDim.x + threadIdx.x;
  if (e < E) atomicAdd(&counts[dst[e]], 1);
}

__global__ void k_blocksum(const int* __restrict__ counts, int* __restrict__ bsum, int N) {
  __shared__ int s[256];
  int i = blockIdx.x * 256 + threadIdx.x;
  s[threadIdx.x] = (i < N) ? counts[i] : 0;
  __syncthreads();
  for (int off = 128; off; off >>= 1) {
    if (threadIdx.x < off) s[threadIdx.x] += s[threadIdx.x + off];
    __syncthreads();
  }
  if (threadIdx.x == 0) bsum[blockIdx.x] = s[0];
}

__global__ void k_scanb(int* bsum, int NB) {
  __shared__ int s[1024];
  int t = threadIdx.x;
  int v = (t < NB) ? bsum[t] : 0;
  s[t] = v;
  __syncthreads();
  for (int off = 1; off < 1024; off <<= 1) {
    int u = (t >= off) ? s[t - off] : 0;
    __syncthreads();
    s[t] += u;
    __syncthreads();
  }
  if (t < NB) bsum[t] = s[t] - v;  // exclusive
}

__global__ void k_scan(const int* __restrict__ counts, const int* __restrict__ boff,
                       int* __restrict__ start, int* __restrict__ cursor, int N, int E) {
  __shared__ int s[256];
  int t = threadIdx.x;
  int i = blockIdx.x * 256 + t;
  int v = (i < N) ? counts[i] : 0;
  s[t] = v;
  __syncthreads();
  for (int off = 1; off < 256; off <<= 1) {
    int u = (t >= off) ? s[t - off] : 0;
    __syncthreads();
    s[t] += u;
    __syncthreads();
  }
  if (i < N) {
    int st = boff[blockIdx.x] + s[t] - v;
    start[i] = st;
    cursor[i] = st;
  }
  if (blockIdx.x == 0 && t == 0) start[N] = E;
}

__global__ void k_scatter(const int* __restrict__ src, const int* __restrict__ dst,
                          int* __restrict__ cursor, int* __restrict__ csr, int E) {
  int e = blockIdx.x * blockDim.x + threadIdx.x;
  if (e < E) {
    int pos = atomicAdd(&cursor[dst[e]], 1);
    csr[pos] = src[e];
  }
}

// ---------- prep: u = W1@al1, v = W1@ar1 (3-vectors) ----------
__global__ void k_prep(const float* __restrict__ W1, const float* __restrict__ al1,
                       const float* __restrict__ ar1, float* __restrict__ uv) {
  int lane = threadIdx.x & 63;
  float a = al1[lane], r = ar1[lane];
#pragma unroll
  for (int i = 0; i < 3; i++) {
    float w = W1[i * 64 + lane];
    float ui = waveSum(w * a);
    float vi = waveSum(w * r);
    if (lane == 0) { uv[i] = ui; uv[3 + i] = vi; }
  }
}

// ---------- layer-1 aggregate (x-space) + fused layer-2 feats ----------
__global__ __launch_bounds__(256) void k_agg1f(
    const float* __restrict__ x, const float* __restrict__ uv,
    const float* __restrict__ W1, const int* __restrict__ start,
    const int* __restrict__ csr, const float* __restrict__ b1,
    const float* __restrict__ W2, const float* __restrict__ al2,
    const float* __restrict__ ar2, __half* __restrict__ h2,
    float* __restrict__ el2, float* __restrict__ er2, int N) {
  __shared__ float sW[64 * 64];
  int tid = threadIdx.x;
  for (int i = tid; i < 4096; i += 256) sW[i] = W2[i];
  __syncthreads();
  int wave = tid >> 6, lane = tid & 63;
  int n = blockIdx.x * 4 + wave;
  if (n >= N) return;
  int beg = __builtin_amdgcn_readfirstlane(start[n]);
  int end = __builtin_amdgcn_readfirstlane(start[n + 1]);
  int deg = end - beg;
  float u0 = uv[0], u1 = uv[1], u2 = uv[2];
  float v0 = uv[3], v1 = uv[4], v2 = uv[5];
  float ernode = x[n * 3] * v0 + x[n * 3 + 1] * v1 + x[n * 3 + 2] * v2;

  float xagg0 = 0.f, xagg1 = 0.f, xagg2 = 0.f;
  if (deg > 0 && deg <= 64) {
    int idx = beg + lane;
    int s = (idx < end) ? csr[idx] : 0;
    s = ((unsigned)s < (unsigned)N) ? s : 0;
    float xs0 = x[s * 3], xs1 = x[s * 3 + 1], xs2 = x[s * 3 + 2];
    float e = xs0 * u0 + xs1 * u1 + xs2 * u2 + ernode;
    e = e > 0.f ? e : 0.2f * e;               // attn leaky_relu(0.2)
    e = (idx < end) ? e : NEG_BIG;
    float m = waveMax(e);
    float q = __expf(e - m);
    float invd = 1.f / waveSum(q);
    float a = q * invd;
    xagg0 = waveSum(a * xs0);
    xagg1 = waveSum(a * xs1);
    xagg2 = waveSum(a * xs2);
  } else if (deg > 64) {
    float m = NEG_BIG, dd = 0.f, q0 = 0.f, q1 = 0.f, q2 = 0.f;
    for (int base = beg; base < end; base += 64) {
      int idx = base + lane;
      int s = (idx < end) ? csr[idx] : 0;
      s = ((unsigned)s < (unsigned)N) ? s : 0;
      float xs0 = x[s * 3], xs1 = x[s * 3 + 1], xs2 = x[s * 3 + 2];
      float e = xs0 * u0 + xs1 * u1 + xs2 * u2 + ernode;
      e = e > 0.f ? e : 0.2f * e;
      e = (idx < end) ? e : NEG_BIG;
      float mn = fmaxf(m, waveMax(e));
      float sc = __expf(m - mn);
      float q = __expf(e - mn);
      dd = dd * sc + waveSum(q);
      q0 = q0 * sc + waveSum(q * xs0);
      q1 = q1 * sc + waveSum(q * xs1);
      q2 = q2 * sc + waveSum(q * xs2);
      m = mn;
    }
    float invd = 1.f / dd;
    xagg0 = q0 * invd; xagg1 = q1 * invd; xagg2 = q2 * invd;
  }
  // o[lane] = xagg @ W1 column lane
  float o = xagg0 * W1[lane] + xagg1 * W1[64 + lane] + xagg2 * W1[128 + lane];
  float r = o + b1[lane];
  r = r > 0.f ? r : 0.01f * r;                // leaky_relu(0.01)
  float acc = 0.f;
#pragma unroll
  for (int k = 0; k < 64; k++) acc += __shfl(r, k, 64) * sW[k * 64 + lane];
  h2[(size_t)n * 64 + lane] = __float2half(acc);
  float e1s = waveSum(acc * al2[lane]);
  float e2s = waveSum(acc * ar2[lane]);
  if (lane == 0) { el2[n] = e1s; er2[n] = e2s; }
}

// ---------- layer-2 aggregate + fused layer-3 feats (h3 padded to 4) ------
__global__ __launch_bounds__(256) void k_agg2f(
    const __half* __restrict__ h2, const float* __restrict__ el,
    const float* __restrict__ er, const int* __restrict__ start,
    const int* __restrict__ csr, const float* __restrict__ b2,
    const float* __restrict__ W3, const float* __restrict__ al3,
    const float* __restrict__ ar3, float* __restrict__ h3, int N) {
  int wave = threadIdx.x >> 6, lane = threadIdx.x & 63;
  int n = blockIdx.x * 4 + wave;
  if (n >= N) return;
  int beg = __builtin_amdgcn_readfirstlane(start[n]);
  int end = __builtin_amdgcn_readfirstlane(start[n + 1]);
  int deg = end - beg;
  float ern = er[n];
  float o = 0.f;

  if (deg > 0 && deg <= 64) {
    int idx = beg + lane;
    int s = (idx < end) ? csr[idx] : 0;
    s = ((unsigned)s < (unsigned)N) ? s : 0;
    float e = el[s] + ern;
    e = e > 0.f ? e : 0.2f * e;
    e = (idx < end) ? e : NEG_BIG;
    float m = waveMax(e);
    float q = __expf(e - m);
    float invd = 1.f / waveSum(q);
    float a = q * invd;
    int j = 0;
    for (; j + 7 < deg; j += 8) {
      int s0 = rlI(s, j),     s1 = rlI(s, j + 1), s2 = rlI(s, j + 2), s3 = rlI(s, j + 3);
      int s4 = rlI(s, j + 4), s5 = rlI(s, j + 5), s6 = rlI(s, j + 6), s7 = rlI(s, j + 7);
      float a0 = rlF(a, j),     a1 = rlF(a, j + 1), a2 = rlF(a, j + 2), a3 = rlF(a, j + 3);
      float a4 = rlF(a, j + 4), a5 = rlF(a, j + 5), a6 = rlF(a, j + 6), a7 = rlF(a, j + 7);
      float h0 = __half2float(h2[(size_t)s0 * 64 + lane]);
      float h1 = __half2float(h2[(size_t)s1 * 64 + lane]);
      float hc2 = __half2float(h2[(size_t)s2 * 64 + lane]);
      float hc3 = __half2float(h2[(size_t)s3 * 64 + lane]);
      float h4 = __half2float(h2[(size_t)s4 * 64 + lane]);
      float h5 = __half2float(h2[(size_t)s5 * 64 + lane]);
      float h6 = __half2float(h2[(size_t)s6 * 64 + lane]);
      float h7 = __half2float(h2[(size_t)s7 * 64 + lane]);
      o += ((a0 * h0 + a1 * h1) + (a2 * hc2 + a3 * hc3)) +
           ((a4 * h4 + a5 * h5) + (a6 * h6 + a7 * h7));
    }
    for (; j + 3 < deg; j += 4) {
      int s0 = rlI(s, j), s1 = rlI(s, j + 1), s2 = rlI(s, j + 2), s3 = rlI(s, j + 3);
      float a0 = rlF(a, j), a1 = rlF(a, j + 1), a2 = rlF(a, j + 2), a3 = rlF(a, j + 3);
      float h0 = __half2float(h2[(size_t)s0 * 64 + lane]);
      float h1 = __half2float(h2[(size_t)s1 * 64 + lane]);
      float hc2 = __half2float(h2[(size_t)s2 * 64 + lane]);
      float hc3 = __half2float(h2[(size_t)s3 * 64 + lane]);
      o += (a0 * h0 + a1 * h1) + (a2 * hc2 + a3 * hc3);
    }
    for (; j < deg; j++) {
      int s0 = rlI(s, j);
      float a0 = rlF(a, j);
      o += a0 * __half2float(h2[(size_t)s0 * 64 + lane]);
    }
  } else if (deg > 64) {
    float m = NEG_BIG, d = 0.f;
    for (int base = beg; base < end; base += 64) {
      int idx = base + lane;
      int s = (idx < end) ? csr[idx] : 0;
      s = ((unsigned)s < (unsigned)N) ? s : 0;
      float e = el[s] + ern;
      e = e > 0.f ? e : 0.2f * e;
      e = (idx < end) ? e : NEG_BIG;
      float mn = fmaxf(m, waveMax(e));
      d = d * __expf(m - mn) + waveSum(__expf(e - mn));
      m = mn;
    }
    float invd = 1.f / d;
    for (int base = beg; base < end; base += 64) {
      int idx = base + lane;
      int s = (idx < end) ? csr[idx] : 0;
      s = ((unsigned)s < (unsigned)N) ? s : 0;
      float e = el[s] + ern;
      e = e > 0.f ? e : 0.2f * e;
      float a = (idx < end) ? __expf(e - m) * invd : 0.f;
      int cnt = end - base; cnt = cnt > 64 ? 64 : cnt;
      for (int j = 0; j < cnt; j++) {
        int s0 = rlI(s, j);
        float a0 = rlF(a, j);
        o += a0 * __half2float(h2[(size_t)s0 * 64 + lane]);
      }
    }
  }
  float r = o + b2[lane];
  r = r > 0.f ? r : 0.01f * r;
  float p0 = waveSum(r * W3[lane * 3 + 0]);
  float p1 = waveSum(r * W3[lane * 3 + 1]);
  float p2 = waveSum(r * W3[lane * 3 + 2]);
  if (lane == 0) {
    h3[n * 4 + 0] = p0; h3[n * 4 + 1] = p1; h3[n * 4 + 2] = p2; h3[n * 4 + 3] = 0.f;
  }
}

// ---------- final aggregate (Fout=3), edge-parallel, logits on the fly ----
__global__ __launch_bounds__(256) void k_agg3(
    const float4* __restrict__ h3, const int* __restrict__ start,
    const int* __restrict__ csr, const float* __restrict__ al3,
    const float* __restrict__ ar3, const float* __restrict__ b,
    float* __restrict__ out, int N) {
  int wave = threadIdx.x >> 6, lane = threadIdx.x & 63;
  int n = blockIdx.x * 4 + wave;
  if (n >= N) return;
  int beg = __builtin_amdgcn_readfirstlane(start[n]);
  int end = __builtin_amdgcn_readfirstlane(start[n + 1]);
  int deg = end - beg;
  float a0c = al3[0], a1c = al3[1], a2c = al3[2];
  float4 hn = h3[n];
  float ern = hn.x * ar3[0] + hn.y * ar3[1] + hn.z * ar3[2];
  float o0 = 0.f, o1 = 0.f, o2 = 0.f;

  if (deg > 0 && deg <= 64) {
    int idx = beg + lane;
    int s = (idx < end) ? csr[idx] : 0;
    s = ((unsigned)s < (unsigned)N) ? s : 0;
    float4 hv = h3[s];                        // 16B gather per lane
    float e = hv.x * a0c + hv.y * a1c + hv.z * a2c + ern;
    e = e > 0.f ? e : 0.2f * e;
    e = (idx < end) ? e : NEG_BIG;
    float m = waveMax(e);
    float q = __expf(e - m);
    float invd = 1.f / waveSum(q);
    float a = q * invd;
    o0 = waveSum(a * hv.x);
    o1 = waveSum(a * hv.y);
    o2 = waveSum(a * hv.z);
  } else if (deg > 64) {
    float m = NEG_BIG, dd = 0.f, q0 = 0.f, q1 = 0.f, q2 = 0.f;
    for (int base = beg; base < end; base += 64) {
      int idx = base + lane;
      int s = (idx < end) ? csr[idx] : 0;
      s = ((unsigned)s < (unsigned)N) ? s : 0;
      float4 hv = h3[s];
      float e = hv.x * a0c + hv.y * a1c + hv.z * a2c + ern;
      e = e > 0.f ? e : 0.2f * e;
      e = (idx < end) ? e : NEG_BIG;
      float mn = fmaxf(m, waveMax(e));
      float sc = __expf(m - mn);
      float q = __expf(e - mn);
      dd = dd * sc + waveSum(q);
      q0 = q0 * sc + waveSum(q * hv.x);
      q1 = q1 * sc + waveSum(q * hv.y);
      q2 = q2 * sc + waveSum(q * hv.z);
      m = mn;
    }
    float invd = 1.f / dd;
    o0 = q0 * invd; o1 = q1 * invd; o2 = q2 * invd;
  }
  if (lane == 0) {
    out[n * 3 + 0] = o0 + b[0];
    out[n * 3 + 1] = o1 + b[1];
    out[n * 3 + 2] = o2 + b[2];
  }
}

extern "C" void kernel_launch(void* const* d_in, const int* in_sizes, int n_in,
                              void* d_out, int out_size, void* d_ws, size_t ws_size,
                              hipStream_t stream) {
  const int N = in_sizes[0] / 3;
  const int E = in_sizes[1];
  const float* feats = (const float*)d_in[0];
  const int* src = (const int*)d_in[1];
  const int* dst = (const int*)d_in[2];
  const float* W1  = (const float*)d_in[3];
  const float* al1 = (const float*)d_in[4];
  const float* ar1 = (const float*)d_in[5];
  const float* b1  = (const float*)d_in[6];
  const float* W2  = (const float*)d_in[7];
  const float* al2 = (const float*)d_in[8];
  const float* ar2 = (const float*)d_in[9];
  const float* b2  = (const float*)d_in[10];
  const float* W3  = (const float*)d_in[11];
  const float* al3 = (const float*)d_in[12];
  const float* ar3 = (const float*)d_in[13];
  const float* b3  = (const float*)d_in[14];

  char* ws = (char*)d_ws;
  size_t off = 0;
  auto alloc = [&](size_t bytes) -> void* {
    void* p = ws + off;
    off = (off + bytes + 255) & ~(size_t)255;
    return p;
  };
  int* counts = (int*)alloc((size_t)N * 4);
  int* startv = (int*)alloc((size_t)(N + 1) * 4);
  int* cursor = (int*)alloc((size_t)N * 4);
  int* csr    = (int*)alloc((size_t)E * 4);
  float* elB  = (float*)alloc((size_t)N * 4);
  float* erB  = (float*)alloc((size_t)N * 4);
  int* bsum   = (int*)alloc(1024 * 4);
  float* uv   = (float*)alloc(64);
  float* h3   = (float*)alloc((size_t)N * 4 * 4);    // padded [N,4]
  __half* h2  = (__half*)alloc((size_t)N * 64 * 2);  // total ~23 MB

  const int NB  = (N + 255) / 256;
  const int NB4 = (N + 3) / 4;
  const int EB  = (E + 255) / 256;

  hipMemsetAsync(counts, 0, (size_t)N * 4, stream);
  k_count<<<EB, 256, 0, stream>>>(dst, counts, E);
  k_blocksum<<<NB, 256, 0, stream>>>(counts, bsum, N);
  k_scanb<<<1, 1024, 0, stream>>>(bsum, NB);
  k_scan<<<NB, 256, 0, stream>>>(counts, bsum, startv, cursor, N, E);
  k_scatter<<<EB, 256, 0, stream>>>(src, dst, cursor, csr, E);
  k_prep<<<1, 64, 0, stream>>>(W1, al1, ar1, uv);

  k_agg1f<<<NB4, 256, 0, stream>>>(feats, uv, W1, startv, csr, b1,
                                   W2, al2, ar2, h2, elB, erB, N);
  k_agg2f<<<NB4, 256, 0, stream>>>(h2, elB, erB, startv, csr, b2,
                                   W3, al3, ar3, h3, N);
  k_agg3<<<NB4, 256, 0, stream>>>((const float4*)h3, startv, csr, al3, ar3, b3,
                                  (float*)d_out, N);
}

// Round 8
// 404.427 us; speedup vs baseline: 1.6908x; 1.2746x over previous
//
#include <hip/hip_runtime.h>
#include <hip/hip_fp16.h>
#include <math.h>

// GAT 3-layer net, v8.
//  - agg1x: 2 nodes/wave, x-space softmax+agg (chunked online), writes
//    x2=leaky(aggx@W1+b1) fp16 and el2/er2 via precomputed W2@al2 / W2@ar2
//    (linearity). NO per-node 64x64 matmul, NO LDS staging here.
//  - k_gemm2: batched h2 = x2@W2, 64-row LDS tiles, broadcast reads,
//    fp32 acc, IN-PLACE (x2 buffer becomes h2) -> ws stays ~23 MB.
//  - agg2f: 2 nodes/wave, half-wave softmax, __half2 row gathers,
//    readlane-broadcast phase B (4x unrolled); rare deg>32 generic path.
//  - agg3: 2 nodes/wave, chunked online, float4 gathers, logits on the fly.
//  - fp32 in/out (proven r3/r4).

#define NEG_BIG (-1e30f)

__device__ inline float waveSum(float v) {
#pragma unroll
  for (int off = 32; off; off >>= 1) v += __shfl_xor(v, off, 64);
  return v;
}

__device__ inline float halfSum(float v) {
#pragma unroll
  for (int off = 16; off; off >>= 1) v += __shfl_xor(v, off, 64);
  return v;
}

__device__ inline float halfMax(float v) {
#pragma unroll
  for (int off = 16; off; off >>= 1) v = fmaxf(v, __shfl_xor(v, off, 64));
  return v;
}

__device__ inline int waveMaxI(int v) {
#pragma unroll
  for (int off = 32; off; off >>= 1) v = max(v, __shfl_xor(v, off, 64));
  return v;
}

__device__ inline int rlI(int v, int l) { return __builtin_amdgcn_readlane(v, l); }
__device__ inline float rlF(float v, int l) {
  return __int_as_float(__builtin_amdgcn_readlane(__float_as_int(v), l));
}

// ---------- CSR build ----------
__global__ void k_count(const int* __restrict__ dst, int* __restrict__ counts, int E) {
  int e = blockIdx.x * blockDim.x + threadIdx.x;
  if (e < E) atomicAdd(&counts[dst[e]], 1);
}

__global__ void k_blocksum(const int* __restrict__ counts, int* __restrict__ bsum, int N) {
  __shared__ int s[256];
  int i = blockIdx.x * 256 + threadIdx.x;
  s[threadIdx.x] = (i < N) ? counts[i] : 0;
  __syncthreads();
  for (int off = 128; off; off >>= 1) {
    if (threadIdx.x < off) s[threadIdx.x] += s[threadIdx.x + off];
    __syncthreads();
  }
  if (threadIdx.x == 0) bsum[blockIdx.x] = s[0];
}

__global__ void k_scanb(int* bsum, int NB) {
  __shared__ int s[1024];
  int t = threadIdx.x;
  int v = (t < NB) ? bsum[t] : 0;
  s[t] = v;
  __syncthreads();
  for (int off = 1; off < 1024; off <<= 1) {
    int u = (t >= off) ? s[t - off] : 0;
    __syncthreads();
    s[t] += u;
    __syncthreads();
  }
  if (t < NB) bsum[t] = s[t] - v;  // exclusive
}

__global__ void k_scan(const int* __restrict__ counts, const int* __restrict__ boff,
                       int* __restrict__ start, int* __restrict__ cursor, int N, int E) {
  __shared__ int s[256];
  int t = threadIdx.x;
  int i = blockIdx.x * 256 + t;
  int v = (i < N) ? counts[i] : 0;
  s[t] = v;
  __syncthreads();
  for (int off = 1; off < 256; off <<= 1) {
    int u = (t >= off) ? s[t - off] : 0;
    __syncthreads();
    s[t] += u;
    __syncthreads();
  }
  if (i < N) {
    int st = boff[blockIdx.x] + s[t] - v;
    start[i] = st;
    cursor[i] = st;
  }
  if (blockIdx.x == 0 && t == 0) start[N] = E;
}

__global__ void k_scatter(const int* __restrict__ src, const int* __restrict__ dst,
                          int* __restrict__ cursor, int* __restrict__ csr, int E) {
  int e = blockIdx.x * blockDim.x + threadIdx.x;
  if (e < E) {
    int pos = atomicAdd(&cursor[dst[e]], 1);
    csr[pos] = src[e];
  }
}

// ---------- prep: uv[0..5] = W1@al1|W1@ar1 ; uvw[8..71]=W2@al2 ; [72..135]=W2@ar2
__global__ void k_prep(const float* __restrict__ W1, const float* __restrict__ al1,
                       const float* __restrict__ ar1, const float* __restrict__ W2,
                       const float* __restrict__ al2, const float* __restrict__ ar2,
                       float* __restrict__ uvw) {
  int lane = threadIdx.x & 63;
  float a = al1[lane], r = ar1[lane];
#pragma unroll
  for (int i = 0; i < 3; ++i) {
    float w = W1[i * 64 + lane];
    float ui = waveSum(w * a);
    float vi = waveSum(w * r);
    if (lane == 0) { uvw[i] = ui; uvw[3 + i] = vi; }
  }
  float sa = 0.f, sr = 0.f;
  for (int j = 0; j < 64; ++j) {
    float w = W2[lane * 64 + j];
    sa = fmaf(w, al2[j], sa);
    sr = fmaf(w, ar2[j], sr);
  }
  uvw[8 + lane] = sa;
  uvw[72 + lane] = sr;
}

// ---------- layer-1: x-space agg (2 nodes/wave) -> x2 fp16, el2/er2 ----------
__global__ __launch_bounds__(256) void k_agg1x(
    const float* __restrict__ x, const float* __restrict__ uvw,
    const float* __restrict__ W1, const float* __restrict__ b1,
    const int* __restrict__ start, const int* __restrict__ csr,
    __half* __restrict__ x2, float* __restrict__ el2, float* __restrict__ er2,
    int N) {
  int tid = threadIdx.x;
  int wave = tid >> 6, lane = tid & 63, hl = lane & 31, half = lane >> 5;
  int pA = blockIdx.x * 8 + wave * 2;
  int pn = pA + half;
  int n = (pn < N) ? pn : 0;
  int beg = start[n], end = start[n + 1];
  float u0 = uvw[0], u1 = uvw[1], u2 = uvw[2];
  float v0 = uvw[3], v1 = uvw[4], v2 = uvw[5];
  float ern = fmaf(x[n * 3], v0, fmaf(x[n * 3 + 1], v1, x[n * 3 + 2] * v2));
  float m = NEG_BIG, d = 0.f, X0 = 0.f, X1 = 0.f, X2 = 0.f;
  for (int base = beg; base < end; base += 32) {
    int idx = base + hl;
    int s = (idx < end) ? csr[idx] : 0;
    s = ((unsigned)s < (unsigned)N) ? s : 0;
    float xs0 = x[s * 3], xs1 = x[s * 3 + 1], xs2 = x[s * 3 + 2];
    float e = fmaf(xs0, u0, fmaf(xs1, u1, fmaf(xs2, u2, ern)));
    e = e > 0.f ? e : 0.2f * e;            // attn leaky_relu(0.2)
    e = (idx < end) ? e : NEG_BIG;
    float mn = fmaxf(m, halfMax(e));
    float sc = __expf(m - mn);
    float q = __expf(e - mn);
    d = d * sc + halfSum(q);
    X0 = X0 * sc + halfSum(q * xs0);
    X1 = X1 * sc + halfSum(q * xs1);
    X2 = X2 * sc + halfSum(q * xs2);
    m = mn;
  }
  float inv = (end > beg) ? 1.f / d : 0.f;
  X0 *= inv; X1 *= inv; X2 *= inv;
  float A0 = rlF(X0, 0), A1 = rlF(X1, 0), A2 = rlF(X2, 0);
  float B0 = rlF(X0, 32), B1 = rlF(X1, 32), B2 = rlF(X2, 32);
  float w1a = W1[lane], w1b = W1[64 + lane], w1c = W1[128 + lane];
  float bb = b1[lane];
  float wal = uvw[8 + lane], war = uvw[72 + lane];
  // node A epilogue (full wave = 64 features)
  {
    float vA = fmaf(A0, w1a, fmaf(A1, w1b, fmaf(A2, w1c, bb)));
    vA = vA > 0.f ? vA : 0.01f * vA;       // leaky_relu(0.01)
    float eA = waveSum(vA * wal);
    float rA = waveSum(vA * war);
    if (pA < N) {
      x2[(size_t)pA * 64 + lane] = __float2half(vA);
      if (lane == 0) { el2[pA] = eA; er2[pA] = rA; }
    }
  }
  // node B epilogue
  {
    int pB = pA + 1;
    float vB = fmaf(B0, w1a, fmaf(B1, w1b, fmaf(B2, w1c, bb)));
    vB = vB > 0.f ? vB : 0.01f * vB;
    float eB = waveSum(vB * wal);
    float rB = waveSum(vB * war);
    if (pB < N) {
      x2[(size_t)pB * 64 + lane] = __float2half(vB);
      if (lane == 0) { el2[pB] = eB; er2[pB] = rB; }
    }
  }
}

// ---------- batched GEMM: h2 = x2 @ W2, in-place (x2 and h2 alias) ----------
__global__ __launch_bounds__(256) void k_gemm2(const __half* x2_in,
                                               const float* __restrict__ W2,
                                               __half* h2_out, int N) {
  __shared__ float sW[64 * 64];  // 16 KB
  __shared__ float sX[64 * 64];  // 16 KB
  int tid = threadIdx.x;
  for (int i = tid; i < 4096; i += 256) sW[i] = W2[i];
  const unsigned* xu = (const unsigned*)x2_in;
  size_t base = (size_t)blockIdx.x * 2048;  // uints (64 rows * 32)
  size_t limit = (size_t)N * 32;
  for (int i = tid; i < 2048; i += 256) {
    size_t gi = base + i;
    unsigned u = (gi < limit) ? xu[gi] : 0u;
    __half2 hh = *(__half2*)&u;
    float2 f = __half22float2(hh);
    sX[2 * i] = f.x;
    sX[2 * i + 1] = f.y;
  }
  __syncthreads();
  int wave = tid >> 6, f = tid & 63;
  int r0 = wave * 16;
  float acc[16];
#pragma unroll
  for (int i = 0; i < 16; ++i) acc[i] = 0.f;
  const float2* sX2 = (const float2*)sX;
  for (int k2 = 0; k2 < 32; ++k2) {
    float wv0 = sW[(2 * k2) * 64 + f];
    float wv1 = sW[(2 * k2 + 1) * 64 + f];
#pragma unroll
    for (int i = 0; i < 16; ++i) {
      float2 xv = sX2[(r0 + i) * 32 + k2];  // broadcast b64 read
      acc[i] = fmaf(xv.x, wv0, fmaf(xv.y, wv1, acc[i]));
    }
  }
  int rowbase = blockIdx.x * 64 + r0;
#pragma unroll
  for (int i = 0; i < 16; ++i) {
    int row = rowbase + i;
    if (row < N) h2_out[(size_t)row * 64 + f] = __float2half(acc[i]);
  }
}

// ---------- layer-2 aggregate (2 nodes/wave) + fused W3 -> h3 ----------
__global__ __launch_bounds__(256) void k_agg2f(
    const __half* __restrict__ h2, const float* __restrict__ el,
    const float* __restrict__ er, const int* __restrict__ start,
    const int* __restrict__ csr, const float* __restrict__ b2,
    const float* __restrict__ W3, float* __restrict__ h3, int N) {
  int tid = threadIdx.x;
  int wave = tid >> 6, lane = tid & 63, hl = lane & 31, half = lane >> 5;
  int pn = blockIdx.x * 8 + wave * 2 + half;
  int n = (pn < N) ? pn : 0;
  int beg = start[n], end = start[n + 1];
  int deg = end - beg;
  int maxd = __builtin_amdgcn_readfirstlane(waveMaxI(deg));
  float ern = er[n];
  float ox = 0.f, oy = 0.f;

  if (maxd <= 32) {
    int idx = beg + hl;
    int s = (idx < end) ? csr[idx] : 0;
    s = ((unsigned)s < (unsigned)N) ? s : 0;
    float e = el[s] + ern;
    e = e > 0.f ? e : 0.2f * e;
    e = (idx < end) ? e : NEG_BIG;
    float mm = halfMax(e);
    float q = __expf(e - mm);
    float dsum = halfSum(q);
    float inv = (deg > 0) ? 1.f / dsum : 0.f;
    float a = q * inv;                      // 0 for invalid lanes
    for (int j = 0; j < maxd; j += 4) {     // j+3 <= 31 always
#pragma unroll
      for (int k = 0; k < 4; ++k) {
        int jk = j + k;
        int sA = rlI(s, jk), sB = rlI(s, jk + 32);
        float aA = rlF(a, jk), aB = rlF(a, jk + 32);
        int sj = half ? sB : sA;
        float aj = half ? aB : aA;
        const __half2* hp = (const __half2*)(h2 + (size_t)sj * 64);
        float2 hf = __half22float2(hp[hl]);
        ox = fmaf(aj, hf.x, ox);
        oy = fmaf(aj, hf.y, oy);
      }
    }
  } else {
    // generic chunked two-pass (rare)
    float m = NEG_BIG, dsum = 0.f;
    for (int base = beg; base < end; base += 32) {
      int idx = base + hl;
      int s = (idx < end) ? csr[idx] : 0;
      s = ((unsigned)s < (unsigned)N) ? s : 0;
      float e = el[s] + ern;
      e = e > 0.f ? e : 0.2f * e;
      e = (idx < end) ? e : NEG_BIG;
      float mn = fmaxf(m, halfMax(e));
      dsum = dsum * __expf(m - mn) + halfSum(__expf(e - mn));
      m = mn;
    }
    float inv = (deg > 0) ? 1.f / dsum : 0.f;
    for (int base = beg; base < end; base += 32) {
      int idx = base + hl;
      int s = (idx < end) ? csr[idx] : 0;
      s = ((unsigned)s < (unsigned)N) ? s : 0;
      float e = el[s] + ern;
      e = e > 0.f ? e : 0.2f * e;
      float a = (idx < end) ? __expf(e - m) * inv : 0.f;
      for (int j = 0; j < 32; ++j) {
        int sA = rlI(s, j), sB = rlI(s, j + 32);
        float aA = rlF(a, j), aB = rlF(a, j + 32);
        int sj = half ? sB : sA;
        float aj = half ? aB : aA;
        const __half2* hp = (const __half2*)(h2 + (size_t)sj * 64);
        float2 hf = __half22float2(hp[hl]);
        ox = fmaf(aj, hf.x, ox);
        oy = fmaf(aj, hf.y, oy);
      }
    }
  }
  // epilogue: r2 = leaky(o + b2) ; p = r2 @ W3 (64->3) per half
  float2 bb = ((const float2*)b2)[hl];
  float r0 = ox + bb.x, r1 = oy + bb.y;
  r0 = r0 > 0.f ? r0 : 0.01f * r0;
  r1 = r1 > 0.f ? r1 : 0.01f * r1;
  int k0 = 2 * hl, k1 = 2 * hl + 1;
  float p0 = halfSum(fmaf(r0, W3[k0 * 3 + 0], r1 * W3[k1 * 3 + 0]));
  float p1 = halfSum(fmaf(r0, W3[k0 * 3 + 1], r1 * W3[k1 * 3 + 1]));
  float p2 = halfSum(fmaf(r0, W3[k0 * 3 + 2], r1 * W3[k1 * 3 + 2]));
  if (hl == 0 && pn < N) {
    h3[n * 4 + 0] = p0; h3[n * 4 + 1] = p1; h3[n * 4 + 2] = p2; h3[n * 4 + 3] = 0.f;
  }
}

// ---------- final aggregate (2 nodes/wave), logits on the fly ----------
__global__ __launch_bounds__(256) void k_agg3(
    const float4* __restrict__ h3, const int* __restrict__ start,
    const int* __restrict__ csr, const float* __restrict__ al3,
    const float* __restrict__ ar3, const float* __restrict__ b,
    float* __restrict__ out, int N) {
  int tid = threadIdx.x;
  int wave = tid >> 6, lane = tid & 63, hl = lane & 31, half = lane >> 5;
  int pn = blockIdx.x * 8 + wave * 2 + half;
  int n = (pn < N) ? pn : 0;
  int beg = start[n], end = start[n + 1];
  float a0c = al3[0], a1c = al3[1], a2c = al3[2];
  float4 hn = h3[n];
  float ern = fmaf(hn.x, ar3[0], fmaf(hn.y, ar3[1], hn.z * ar3[2]));
  float m = NEG_BIG, d = 0.f, Q0 = 0.f, Q1 = 0.f, Q2 = 0.f;
  for (int base = beg; base < end; base += 32) {
    int idx = base + hl;
    int s = (idx < end) ? csr[idx] : 0;
    s = ((unsigned)s < (unsigned)N) ? s : 0;
    float4 hv = h3[s];
    float e = fmaf(hv.x, a0c, fmaf(hv.y, a1c, fmaf(hv.z, a2c, ern)));
    e = e > 0.f ? e : 0.2f * e;
    e = (idx < end) ? e : NEG_BIG;
    float mn = fmaxf(m, halfMax(e));
    float sc = __expf(m - mn);
    float q = __expf(e - mn);
    d = d * sc + halfSum(q);
    Q0 = Q0 * sc + halfSum(q * hv.x);
    Q1 = Q1 * sc + halfSum(q * hv.y);
    Q2 = Q2 * sc + halfSum(q * hv.z);
    m = mn;
  }
  float inv = (end > beg) ? 1.f / d : 0.f;
  if (hl == 0 && pn < N) {
    out[n * 3 + 0] = fmaf(Q0, inv, b[0]);
    out[n * 3 + 1] = fmaf(Q1, inv, b[1]);
    out[n * 3 + 2] = fmaf(Q2, inv, b[2]);
  }
}

extern "C" void kernel_launch(void* const* d_in, const int* in_sizes, int n_in,
                              void* d_out, int out_size, void* d_ws, size_t ws_size,
                              hipStream_t stream) {
  const int N = in_sizes[0] / 3;
  const int E = in_sizes[1];
  const float* feats = (const float*)d_in[0];
  const int* src = (const int*)d_in[1];
  const int* dst = (const int*)d_in[2];
  const float* W1  = (const float*)d_in[3];
  const float* al1 = (const float*)d_in[4];
  const float* ar1 = (const float*)d_in[5];
  const float* b1  = (const float*)d_in[6];
  const float* W2  = (const float*)d_in[7];
  const float* al2 = (const float*)d_in[8];
  const float* ar2 = (const float*)d_in[9];
  const float* b2  = (const float*)d_in[10];
  const float* W3  = (const float*)d_in[11];
  const float* al3 = (const float*)d_in[12];
  const float* ar3 = (const float*)d_in[13];
  const float* b3  = (const float*)d_in[14];

  char* ws = (char*)d_ws;
  size_t off = 0;
  auto alloc = [&](size_t bytes) -> void* {
    void* p = ws + off;
    off = (off + bytes + 255) & ~(size_t)255;
    return p;
  };
  int* counts = (int*)alloc((size_t)N * 4);
  int* startv = (int*)alloc((size_t)(N + 1) * 4);
  int* cursor = (int*)alloc((size_t)N * 4);
  int* csr    = (int*)alloc((size_t)E * 4);
  float* elB  = (float*)alloc((size_t)N * 4);
  float* erB  = (float*)alloc((size_t)N * 4);
  int* bsum   = (int*)alloc(1024 * 4);
  float* uvw  = (float*)alloc(1024);
  float* h3   = (float*)alloc((size_t)N * 4 * 4);      // padded [N,4] fp32
  __half* x2  = (__half*)alloc((size_t)N * 64 * 2);    // x2, then h2 in-place
  // total ~23 MB (proven-safe scale)

  const int NB  = (N + 255) / 256;
  const int NB8 = (N + 7) / 8;
  const int GB  = (N + 63) / 64;
  const int EB  = (E + 255) / 256;

  hipMemsetAsync(counts, 0, (size_t)N * 4, stream);
  k_count<<<EB, 256, 0, stream>>>(dst, counts, E);
  k_blocksum<<<NB, 256, 0, stream>>>(counts, bsum, N);
  k_scanb<<<1, 1024, 0, stream>>>(bsum, NB);
  k_scan<<<NB, 256, 0, stream>>>(counts, bsum, startv, cursor, N, E);
  k_scatter<<<EB, 256, 0, stream>>>(src, dst, cursor, csr, E);
  k_prep<<<1, 64, 0, stream>>>(W1, al1, ar1, W2, al2, ar2, uvw);

  k_agg1x<<<NB8, 256, 0, stream>>>(feats, uvw, W1, b1, startv, csr,
                                   x2, elB, erB, N);
  k_gemm2<<<GB, 256, 0, stream>>>(x2, W2, x2, N);   // in-place x2 -> h2
  k_agg2f<<<NB8, 256, 0, stream>>>(x2, elB, erB, startv, csr, b2, W3, h3, N);
  k_agg3<<<NB8, 256, 0, stream>>>((const float4*)h3, startv, csr, al3, ar3, b3,
                                  (float*)d_out, N);
}

// Round 9
// 361.545 us; speedup vs baseline: 1.8914x; 1.1186x over previous
//
#include <hip/hip_runtime.h>
#include <hip/hip_fp16.h>
#include <math.h>

// GAT 3-layer net, v9.
//  - r8 forensics: k_scatter WRITE_SIZE = 64B * E exactly -> full-line
//    writeback per random 4B csr write (8 XCD L2s never share lines).
//    Fix: XCD-partitioned scatter (blockIdx&7 -> dst range slice); each
//    XCD's csr slice (800KB) stays L2-resident, writes back once.
//    Reads replicated 8x but L3-absorbed.
//  - x4[n] = (x,y,z, u·x) + er1[n]=v·x precomputed -> agg1x per edge is
//    one float4 gather + 1 add. Same for layer 3: h3.w = el3.
//  - Rest as v8 (2 nodes/wave, halfSum softmax, gemm2 LDS tiles, fp16 h2).

#define NEG_BIG (-1e30f)

__device__ inline float waveSum(float v) {
#pragma unroll
  for (int off = 32; off; off >>= 1) v += __shfl_xor(v, off, 64);
  return v;
}

__device__ inline float halfSum(float v) {
#pragma unroll
  for (int off = 16; off; off >>= 1) v += __shfl_xor(v, off, 64);
  return v;
}

__device__ inline float halfMax(float v) {
#pragma unroll
  for (int off = 16; off; off >>= 1) v = fmaxf(v, __shfl_xor(v, off, 64));
  return v;
}

__device__ inline int waveMaxI(int v) {
#pragma unroll
  for (int off = 32; off; off >>= 1) v = max(v, __shfl_xor(v, off, 64));
  return v;
}

__device__ inline int rlI(int v, int l) { return __builtin_amdgcn_readlane(v, l); }
__device__ inline float rlF(float v, int l) {
  return __int_as_float(__builtin_amdgcn_readlane(__float_as_int(v), l));
}

// ---------- CSR build ----------
__global__ void k_count(const int* __restrict__ dst, int* __restrict__ counts, int E) {
  int e = blockIdx.x * blockDim.x + threadIdx.x;
  if (e < E) atomicAdd(&counts[dst[e]], 1);
}

__global__ void k_blocksum(const int* __restrict__ counts, int* __restrict__ bsum, int N) {
  __shared__ int s[256];
  int i = blockIdx.x * 256 + threadIdx.x;
  s[threadIdx.x] = (i < N) ? counts[i] : 0;
  __syncthreads();
  for (int off = 128; off; off >>= 1) {
    if (threadIdx.x < off) s[threadIdx.x] += s[threadIdx.x + off];
    __syncthreads();
  }
  if (threadIdx.x == 0) bsum[blockIdx.x] = s[0];
}

__global__ void k_scanb(int* bsum, int NB) {
  __shared__ int s[1024];
  int t = threadIdx.x;
  int v = (t < NB) ? bsum[t] : 0;
  s[t] = v;
  __syncthreads();
  for (int off = 1; off < 1024; off <<= 1) {
    int u = (t >= off) ? s[t - off] : 0;
    __syncthreads();
    s[t] += u;
    __syncthreads();
  }
  if (t < NB) bsum[t] = s[t] - v;  // exclusive
}

__global__ void k_scan(const int* __restrict__ counts, const int* __restrict__ boff,
                       int* __restrict__ start, int* __restrict__ cursor, int N, int E) {
  __shared__ int s[256];
  int t = threadIdx.x;
  int i = blockIdx.x * 256 + t;
  int v = (i < N) ? counts[i] : 0;
  s[t] = v;
  __syncthreads();
  for (int off = 1; off < 256; off <<= 1) {
    int u = (t >= off) ? s[t - off] : 0;
    __syncthreads();
    s[t] += u;
    __syncthreads();
  }
  if (i < N) {
    int st = boff[blockIdx.x] + s[t] - v;
    start[i] = st;
    cursor[i] = st;
  }
  if (blockIdx.x == 0 && t == 0) start[N] = E;
}

// XCD-partitioned scatter: blockIdx&7 selects a dst-range slice so each
// XCD's csr writes stay in its own L2 (kills 16x line-writeback amp).
__global__ void k_scatter8(const int* __restrict__ src, const int* __restrict__ dst,
                           int* __restrict__ cursor, int* __restrict__ csr,
                           int E, int N) {
  int gid = blockIdx.x & 7;
  int e = (blockIdx.x >> 3) * 256 + threadIdx.x;
  if (e >= E) return;
  int dd = dst[e];
  int lo = (int)(((long long)N * gid) >> 3);
  int hi = (int)(((long long)N * (gid + 1)) >> 3);
  if (dd >= lo && dd < hi) {
    int pos = atomicAdd(&cursor[dd], 1);
    csr[pos] = src[e];
  }
}

// ---------- prep: uvw[0..5]=W1@al1|W1@ar1; [8..71]=W2@al2; [72..135]=W2@ar2
__global__ void k_prep(const float* __restrict__ W1, const float* __restrict__ al1,
                       const float* __restrict__ ar1, const float* __restrict__ W2,
                       const float* __restrict__ al2, const float* __restrict__ ar2,
                       float* __restrict__ uvw) {
  int lane = threadIdx.x & 63;
  float a = al1[lane], r = ar1[lane];
#pragma unroll
  for (int i = 0; i < 3; ++i) {
    float w = W1[i * 64 + lane];
    float ui = waveSum(w * a);
    float vi = waveSum(w * r);
    if (lane == 0) { uvw[i] = ui; uvw[3 + i] = vi; }
  }
  float sa = 0.f, sr = 0.f;
  for (int j = 0; j < 64; ++j) {
    float w = W2[lane * 64 + j];
    sa = fmaf(w, al2[j], sa);
    sr = fmaf(w, ar2[j], sr);
  }
  uvw[8 + lane] = sa;
  uvw[72 + lane] = sr;
}

// ---------- pad x + per-node layer-1 logits: x4=(x, u·x), er1=v·x ----------
__global__ void k_padx(const float* __restrict__ x, const float* __restrict__ uvw,
                       float4* __restrict__ x4, float* __restrict__ er1, int N) {
  int n = blockIdx.x * blockDim.x + threadIdx.x;
  if (n >= N) return;
  float x0 = x[n * 3], x1 = x[n * 3 + 1], x2 = x[n * 3 + 2];
  float el = fmaf(x0, uvw[0], fmaf(x1, uvw[1], x2 * uvw[2]));
  float er = fmaf(x0, uvw[3], fmaf(x1, uvw[4], x2 * uvw[5]));
  x4[n] = make_float4(x0, x1, x2, el);
  er1[n] = er;
}

// ---------- layer-1: x-space agg (2 nodes/wave) -> x2 fp16, el2/er2 --------
__global__ __launch_bounds__(256) void k_agg1x(
    const float4* __restrict__ x4, const float* __restrict__ er1,
    const float* __restrict__ uvw, const float* __restrict__ W1,
    const float* __restrict__ b1, const int* __restrict__ start,
    const int* __restrict__ csr, __half* __restrict__ x2,
    float* __restrict__ el2, float* __restrict__ er2, int N) {
  int tid = threadIdx.x;
  int wave = tid >> 6, lane = tid & 63, hl = lane & 31, half = lane >> 5;
  int pA = blockIdx.x * 8 + wave * 2;
  int pn = pA + half;
  int n = (pn < N) ? pn : 0;
  int beg = start[n], end = start[n + 1];
  float ern = er1[n];
  float m = NEG_BIG, d = 0.f, X0 = 0.f, X1 = 0.f, X2 = 0.f;
  for (int base = beg; base < end; base += 32) {
    int idx = base + hl;
    int s = (idx < end) ? csr[idx] : 0;
    s = ((unsigned)s < (unsigned)N) ? s : 0;
    float4 hv = x4[s];                      // one 16B gather per edge
    float e = hv.w + ern;
    e = e > 0.f ? e : 0.2f * e;             // attn leaky_relu(0.2)
    e = (idx < end) ? e : NEG_BIG;
    float mn = fmaxf(m, halfMax(e));
    float sc = __expf(m - mn);
    float q = __expf(e - mn);
    d = d * sc + halfSum(q);
    X0 = X0 * sc + halfSum(q * hv.x);
    X1 = X1 * sc + halfSum(q * hv.y);
    X2 = X2 * sc + halfSum(q * hv.z);
    m = mn;
  }
  float inv = (end > beg) ? 1.f / d : 0.f;
  X0 *= inv; X1 *= inv; X2 *= inv;
  float A0 = rlF(X0, 0), A1 = rlF(X1, 0), A2 = rlF(X2, 0);
  float B0 = rlF(X0, 32), B1 = rlF(X1, 32), B2 = rlF(X2, 32);
  float w1a = W1[lane], w1b = W1[64 + lane], w1c = W1[128 + lane];
  float bb = b1[lane];
  float wal = uvw[8 + lane], war = uvw[72 + lane];
  {
    float vA = fmaf(A0, w1a, fmaf(A1, w1b, fmaf(A2, w1c, bb)));
    vA = vA > 0.f ? vA : 0.01f * vA;        // leaky_relu(0.01)
    float eA = waveSum(vA * wal);
    float rA = waveSum(vA * war);
    if (pA < N) {
      x2[(size_t)pA * 64 + lane] = __float2half(vA);
      if (lane == 0) { el2[pA] = eA; er2[pA] = rA; }
    }
  }
  {
    int pB = pA + 1;
    float vB = fmaf(B0, w1a, fmaf(B1, w1b, fmaf(B2, w1c, bb)));
    vB = vB > 0.f ? vB : 0.01f * vB;
    float eB = waveSum(vB * wal);
    float rB = waveSum(vB * war);
    if (pB < N) {
      x2[(size_t)pB * 64 + lane] = __float2half(vB);
      if (lane == 0) { el2[pB] = eB; er2[pB] = rB; }
    }
  }
}

// ---------- batched GEMM: h2 = x2 @ W2, in-place ----------
__global__ __launch_bounds__(256) void k_gemm2(const __half* x2_in,
                                               const float* __restrict__ W2,
                                               __half* h2_out, int N) {
  __shared__ float sW[64 * 64];
  __shared__ float sX[64 * 64];
  int tid = threadIdx.x;
  for (int i = tid; i < 4096; i += 256) sW[i] = W2[i];
  const unsigned* xu = (const unsigned*)x2_in;
  size_t base = (size_t)blockIdx.x * 2048;
  size_t limit = (size_t)N * 32;
  for (int i = tid; i < 2048; i += 256) {
    size_t gi = base + i;
    unsigned u = (gi < limit) ? xu[gi] : 0u;
    __half2 hh = *(__half2*)&u;
    float2 f = __half22float2(hh);
    sX[2 * i] = f.x;
    sX[2 * i + 1] = f.y;
  }
  __syncthreads();
  int wave = tid >> 6, f = tid & 63;
  int r0 = wave * 16;
  float acc[16];
#pragma unroll
  for (int i = 0; i < 16; ++i) acc[i] = 0.f;
  const float2* sX2 = (const float2*)sX;
  for (int k2 = 0; k2 < 32; ++k2) {
    float wv0 = sW[(2 * k2) * 64 + f];
    float wv1 = sW[(2 * k2 + 1) * 64 + f];
#pragma unroll
    for (int i = 0; i < 16; ++i) {
      float2 xv = sX2[(r0 + i) * 32 + k2];
      acc[i] = fmaf(xv.x, wv0, fmaf(xv.y, wv1, acc[i]));
    }
  }
  int rowbase = blockIdx.x * 64 + r0;
#pragma unroll
  for (int i = 0; i < 16; ++i) {
    int row = rowbase + i;
    if (row < N) h2_out[(size_t)row * 64 + f] = __float2half(acc[i]);
  }
}

// ---------- layer-2 aggregate (2 nodes/wave) + fused W3 -> h3 (w=el3) ------
__global__ __launch_bounds__(256) void k_agg2f(
    const __half* __restrict__ h2, const float* __restrict__ el,
    const float* __restrict__ er, const int* __restrict__ start,
    const int* __restrict__ csr, const float* __restrict__ b2,
    const float* __restrict__ W3, const float* __restrict__ al3,
    float* __restrict__ h3, int N) {
  int tid = threadIdx.x;
  int wave = tid >> 6, lane = tid & 63, hl = lane & 31, half = lane >> 5;
  int pn = blockIdx.x * 8 + wave * 2 + half;
  int n = (pn < N) ? pn : 0;
  int beg = start[n], end = start[n + 1];
  int deg = end - beg;
  int maxd = __builtin_amdgcn_readfirstlane(waveMaxI(deg));
  float ern = er[n];
  float ox = 0.f, oy = 0.f;

  if (maxd <= 32) {
    int idx = beg + hl;
    int s = (idx < end) ? csr[idx] : 0;
    s = ((unsigned)s < (unsigned)N) ? s : 0;
    float e = el[s] + ern;
    e = e > 0.f ? e : 0.2f * e;
    e = (idx < end) ? e : NEG_BIG;
    float mm = halfMax(e);
    float q = __expf(e - mm);
    float dsum = halfSum(q);
    float inv = (deg > 0) ? 1.f / dsum : 0.f;
    float a = q * inv;
    for (int j = 0; j < maxd; j += 4) {
#pragma unroll
      for (int k = 0; k < 4; ++k) {
        int jk = j + k;
        int sA = rlI(s, jk), sB = rlI(s, jk + 32);
        float aA = rlF(a, jk), aB = rlF(a, jk + 32);
        int sj = half ? sB : sA;
        float aj = half ? aB : aA;
        const __half2* hp = (const __half2*)(h2 + (size_t)sj * 64);
        float2 hf = __half22float2(hp[hl]);
        ox = fmaf(aj, hf.x, ox);
        oy = fmaf(aj, hf.y, oy);
      }
    }
  } else {
    float m = NEG_BIG, dsum = 0.f;
    for (int base = beg; base < end; base += 32) {
      int idx = base + hl;
      int s = (idx < end) ? csr[idx] : 0;
      s = ((unsigned)s < (unsigned)N) ? s : 0;
      float e = el[s] + ern;
      e = e > 0.f ? e : 0.2f * e;
      e = (idx < end) ? e : NEG_BIG;
      float mn = fmaxf(m, halfMax(e));
      dsum = dsum * __expf(m - mn) + halfSum(__expf(e - mn));
      m = mn;
    }
    float inv = (deg > 0) ? 1.f / dsum : 0.f;
    for (int base = beg; base < end; base += 32) {
      int idx = base + hl;
      int s = (idx < end) ? csr[idx] : 0;
      s = ((unsigned)s < (unsigned)N) ? s : 0;
      float e = el[s] + ern;
      e = e > 0.f ? e : 0.2f * e;
      float a = (idx < end) ? __expf(e - m) * inv : 0.f;
      for (int j = 0; j < 32; ++j) {
        int sA = rlI(s, j), sB = rlI(s, j + 32);
        float aA = rlF(a, j), aB = rlF(a, j + 32);
        int sj = half ? sB : sA;
        float aj = half ? aB : aA;
        const __half2* hp = (const __half2*)(h2 + (size_t)sj * 64);
        float2 hf = __half22float2(hp[hl]);
        ox = fmaf(aj, hf.x, ox);
        oy = fmaf(aj, hf.y, oy);
      }
    }
  }
  float2 bb = ((const float2*)b2)[hl];
  float r0 = ox + bb.x, r1 = oy + bb.y;
  r0 = r0 > 0.f ? r0 : 0.01f * r0;
  r1 = r1 > 0.f ? r1 : 0.01f * r1;
  int k0 = 2 * hl, k1 = 2 * hl + 1;
  float p0 = halfSum(fmaf(r0, W3[k0 * 3 + 0], r1 * W3[k1 * 3 + 0]));
  float p1 = halfSum(fmaf(r0, W3[k0 * 3 + 1], r1 * W3[k1 * 3 + 1]));
  float p2 = halfSum(fmaf(r0, W3[k0 * 3 + 2], r1 * W3[k1 * 3 + 2]));
  if (hl == 0 && pn < N) {
    float el3 = fmaf(p0, al3[0], fmaf(p1, al3[1], p2 * al3[2]));
    h3[n * 4 + 0] = p0; h3[n * 4 + 1] = p1; h3[n * 4 + 2] = p2; h3[n * 4 + 3] = el3;
  }
}

// ---------- final aggregate (2 nodes/wave), logits in h3.w ----------
__global__ __launch_bounds__(256) void k_agg3(
    const float4* __restrict__ h3, const int* __restrict__ start,
    const int* __restrict__ csr, const float* __restrict__ ar3,
    const float* __restrict__ b, float* __restrict__ out, int N) {
  int tid = threadIdx.x;
  int wave = tid >> 6, lane = tid & 63, hl = lane & 31, half = lane >> 5;
  int pn = blockIdx.x * 8 + wave * 2 + half;
  int n = (pn < N) ? pn : 0;
  int beg = start[n], end = start[n + 1];
  float4 hn = h3[n];
  float ern = fmaf(hn.x, ar3[0], fmaf(hn.y, ar3[1], hn.z * ar3[2]));
  float m = NEG_BIG, d = 0.f, Q0 = 0.f, Q1 = 0.f, Q2 = 0.f;
  for (int base = beg; base < end; base += 32) {
    int idx = base + hl;
    int s = (idx < end) ? csr[idx] : 0;
    s = ((unsigned)s < (unsigned)N) ? s : 0;
    float4 hv = h3[s];
    float e = hv.w + ern;
    e = e > 0.f ? e : 0.2f * e;
    e = (idx < end) ? e : NEG_BIG;
    float mn = fmaxf(m, halfMax(e));
    float sc = __expf(m - mn);
    float q = __expf(e - mn);
    d = d * sc + halfSum(q);
    Q0 = Q0 * sc + halfSum(q * hv.x);
    Q1 = Q1 * sc + halfSum(q * hv.y);
    Q2 = Q2 * sc + halfSum(q * hv.z);
    m = mn;
  }
  float inv = (end > beg) ? 1.f / d : 0.f;
  if (hl == 0 && pn < N) {
    out[n * 3 + 0] = fmaf(Q0, inv, b[0]);
    out[n * 3 + 1] = fmaf(Q1, inv, b[1]);
    out[n * 3 + 2] = fmaf(Q2, inv, b[2]);
  }
}

extern "C" void kernel_launch(void* const* d_in, const int* in_sizes, int n_in,
                              void* d_out, int out_size, void* d_ws, size_t ws_size,
                              hipStream_t stream) {
  const int N = in_sizes[0] / 3;
  const int E = in_sizes[1];
  const float* feats = (const float*)d_in[0];
  const int* src = (const int*)d_in[1];
  const int* dst = (const int*)d_in[2];
  const float* W1  = (const float*)d_in[3];
  const float* al1 = (const float*)d_in[4];
  const float* ar1 = (const float*)d_in[5];
  const float* b1  = (const float*)d_in[6];
  const float* W2  = (const float*)d_in[7];
  const float* al2 = (const float*)d_in[8];
  const float* ar2 = (const float*)d_in[9];
  const float* b2  = (const float*)d_in[10];
  const float* W3  = (const float*)d_in[11];
  const float* al3 = (const float*)d_in[12];
  const float* ar3 = (const float*)d_in[13];
  const float* b3  = (const float*)d_in[14];

  char* ws = (char*)d_ws;
  size_t off = 0;
  auto alloc = [&](size_t bytes) -> void* {
    void* p = ws + off;
    off = (off + bytes + 255) & ~(size_t)255;
    return p;
  };
  int* counts = (int*)alloc((size_t)N * 4);
  int* startv = (int*)alloc((size_t)(N + 1) * 4);
  int* cursor = (int*)alloc((size_t)N * 4);
  int* csr    = (int*)alloc((size_t)E * 4);
  float* elB  = (float*)alloc((size_t)N * 4);
  float* erB  = (float*)alloc((size_t)N * 4);
  float* er1  = (float*)alloc((size_t)N * 4);
  int* bsum   = (int*)alloc(1024 * 4);
  float* uvw  = (float*)alloc(1024);
  float* h3   = (float*)alloc((size_t)N * 4 * 4);      // [N,4], w=el3
  float4* x4  = (float4*)alloc((size_t)N * 16);        // (x, u·x)
  __half* x2  = (__half*)alloc((size_t)N * 64 * 2);    // x2, then h2 in-place
  // total ~26.5 MB

  const int NB  = (N + 255) / 256;
  const int NB8 = (N + 7) / 8;
  const int GB  = (N + 63) / 64;
  const int EB  = (E + 255) / 256;

  hipMemsetAsync(counts, 0, (size_t)N * 4, stream);
  k_count<<<EB, 256, 0, stream>>>(dst, counts, E);
  k_prep<<<1, 64, 0, stream>>>(W1, al1, ar1, W2, al2, ar2, uvw);
  k_padx<<<NB, 256, 0, stream>>>(feats, uvw, x4, er1, N);
  k_blocksum<<<NB, 256, 0, stream>>>(counts, bsum, N);
  k_scanb<<<1, 1024, 0, stream>>>(bsum, NB);
  k_scan<<<NB, 256, 0, stream>>>(counts, bsum, startv, cursor, N, E);
  k_scatter8<<<EB * 8, 256, 0, stream>>>(src, dst, cursor, csr, E, N);

  k_agg1x<<<NB8, 256, 0, stream>>>(x4, er1, uvw, W1, b1, startv, csr,
                                   x2, elB, erB, N);
  k_gemm2<<<GB, 256, 0, stream>>>(x2, W2, x2, N);   // in-place x2 -> h2
  k_agg2f<<<NB8, 256, 0, stream>>>(x2, elB, erB, startv, csr, b2, W3, al3, h3, N);
  k_agg3<<<NB8, 256, 0, stream>>>((const float4*)h3, startv, csr, ar3, b3,
                                  (float*)d_out, N);
}